// Round 2
// baseline (6855.721 us; speedup 1.0000x reference)
//
#include <hip/hip_runtime.h>
#include <math.h>

#define D_MODEL 1024
#define D_SAE   16384
#define BATCH   4096
#define NTOT    (1ull * BATCH * D_SAE)
#define LN_EPS  1e-8
#define EPS_M   1e-3f        // |fp32 score - fp64 score| safe band half-width
#define ROW_CAP 256
#define CAND_CAP  (4 * 1024 * 1024)
#define CAND2_CAP 65536
#define COARSE_MARGIN 32768  // elements between extraction floor and rank-kB

// ---------- block (256-thread) reductions ----------
__device__ inline double blockReduceSum256(double v, double* lds) {
#pragma unroll
  for (int off = 32; off > 0; off >>= 1) v += __shfl_down(v, off, 64);
  int lane = threadIdx.x & 63, wid = threadIdx.x >> 6;
  __syncthreads();
  if (lane == 0) lds[wid] = v;
  __syncthreads();
  return lds[0] + lds[1] + lds[2] + lds[3];
}
__device__ inline int blockReduceSumInt256(int v, int* lds) {
#pragma unroll
  for (int off = 32; off > 0; off >>= 1) v += __shfl_down(v, off, 64);
  int lane = threadIdx.x & 63, wid = threadIdx.x >> 6;
  __syncthreads();
  if (lane == 0) lds[wid] = v;
  __syncthreads();
  return lds[0] + lds[1] + lds[2] + lds[3];
}

// wave-aggregated append; returns position (or -1)
__device__ inline int wave_append(bool pred, int* counter) {
  unsigned long long m = __ballot(pred);
  int lane = threadIdx.x & 63;
  int pos = -1;
  if (m) {
    int ldr = __ffsll((long long)m) - 1;
    int base = 0;
    if (lane == ldr) base = atomicAdd(counter, __popcll(m));
    base = __shfl(base, ldr, 64);
    if (pred) pos = base + __popcll(m & ((1ull << lane) - 1ull));
  }
  return pos;
}

// ---------- per-thread fp64 LN chain: thread t owns elements t*4..t*4+3 ----------
__device__ inline void ln_row_fp64(const float* __restrict__ row, double* lds, double d[4]) {
  int t = threadIdx.x;
  float4 s4 = *(const float4*)(row + t * 4);
  float4 t4 = *(const float4*)(row + D_MODEL + t * 4);
  double s[4] = {s4.x, s4.y, s4.z, s4.w};
  double tt[4] = {t4.x, t4.y, t4.z, t4.w};
  double ms = blockReduceSum256(s[0] + s[1] + s[2] + s[3], lds) / D_MODEL;
  double mt = blockReduceSum256(tt[0] + tt[1] + tt[2] + tt[3], lds) / D_MODEL;
  double vs = 0, vt = 0;
#pragma unroll
  for (int i = 0; i < 4; i++) { double a = s[i] - ms; vs += a * a; a = tt[i] - mt; vt += a * a; }
  vs = blockReduceSum256(vs, lds) / D_MODEL;
  vt = blockReduceSum256(vt, lds) / D_MODEL;
  double rs = sqrt(vs + LN_EPS), rt = sqrt(vt + LN_EPS);
  double u[4];
#pragma unroll
  for (int i = 0; i < 4; i++) u[i] = (tt[i] - mt) / rt - (s[i] - ms) / rs;
  double mu = blockReduceSum256(u[0] + u[1] + u[2] + u[3], lds) / D_MODEL;
  double vu = 0;
#pragma unroll
  for (int i = 0; i < 4; i++) { double a = u[i] - mu; vu += a * a; }
  vu = blockReduceSum256(vu, lds) / D_MODEL;
  double ru = sqrt(vu + LN_EPS);
#pragma unroll
  for (int i = 0; i < 4; i++) d[i] = (u[i] - mu) / ru;
}

// ---------- LN to fp32 output ----------
__global__ __launch_bounds__(256) void ln_kernel(const float* __restrict__ x,
                                                 float* __restrict__ diff32) {
  __shared__ double lds[4];
  int b = blockIdx.x, t = threadIdx.x;
  double d[4];
  ln_row_fp64(x + (size_t)b * (2 * D_MODEL), lds, d);
  float f[4] = {(float)d[0], (float)d[1], (float)d[2], (float)d[3]};
  *(float4*)(diff32 + (size_t)b * D_MODEL + t * 4) = *(float4*)f;
}

// ---------- dec_norms in fp64 ----------
__global__ __launch_bounds__(256) void norm_kernel(const float* __restrict__ Wdec,
                                                   double* __restrict__ g64, float* __restrict__ g32) {
  __shared__ double lds[4];
  int j = blockIdx.x, t = threadIdx.x;
  float4 w = *(const float4*)(Wdec + (size_t)j * D_MODEL + t * 4);
  double a = (double)w.x * w.x + (double)w.y * w.y + (double)w.z * w.z + (double)w.w * w.w;
  double sum = blockReduceSum256(a, lds);
  if (t == 0) { double g = sqrt(sum); g64[j] = g; g32[j] = (float)g; }
}

// ---------- fp32 score GEMM: MODE 0 = histogram, MODE 1 = extract ----------
template <int MODE>
__global__ __launch_bounds__(256) void gemm_kernel(
    const float* __restrict__ A, const float* __restrict__ W,
    const float* __restrict__ benc, const float* __restrict__ g32,
    int* __restrict__ ghist, int* __restrict__ ctrl,
    int* __restrict__ cand_idx, float* __restrict__ cand_sc) {
  __shared__ float As[32][64];
  __shared__ float Bs[32][64];
  __shared__ int h[2048];
  if (MODE == 0) { for (int i = threadIdx.x; i < 2048; i += 256) h[i] = 0; }
  const int tid = threadIdx.x;
  const int tx = tid & 15, ty = tid >> 4;
  const int row0 = blockIdx.y * 64, col0 = blockIdx.x * 64;
  const int ra = tid >> 3;
  const int ka = (tid & 7) * 4;
  const int kb = tid >> 4;
  const int cb = (tid & 15) * 4;
  float acc[4][4] = {{0.f}};

  for (int k0 = 0; k0 < D_MODEL; k0 += 32) {
    float4 a0 = *(const float4*)(A + (size_t)(row0 + ra) * D_MODEL + k0 + ka);
    float4 a1 = *(const float4*)(A + (size_t)(row0 + ra + 32) * D_MODEL + k0 + ka);
    float4 b0 = *(const float4*)(W + (size_t)(k0 + kb) * D_SAE + col0 + cb);
    float4 b1 = *(const float4*)(W + (size_t)(k0 + kb + 16) * D_SAE + col0 + cb);
    __syncthreads();
    As[ka + 0][ra] = a0.x; As[ka + 1][ra] = a0.y; As[ka + 2][ra] = a0.z; As[ka + 3][ra] = a0.w;
    As[ka + 0][ra + 32] = a1.x; As[ka + 1][ra + 32] = a1.y; As[ka + 2][ra + 32] = a1.z; As[ka + 3][ra + 32] = a1.w;
    *(float4*)&Bs[kb][cb] = b0;
    *(float4*)&Bs[kb + 16][cb] = b1;
    __syncthreads();
#pragma unroll
    for (int kk = 0; kk < 32; kk++) {
      float4 a4 = *(const float4*)&As[kk][ty * 4];
      float4 b4 = *(const float4*)&Bs[kk][tx * 4];
      float av[4] = {a4.x, a4.y, a4.z, a4.w};
      float bv[4] = {b4.x, b4.y, b4.z, b4.w};
#pragma unroll
      for (int ii = 0; ii < 4; ii++)
#pragma unroll
        for (int jj = 0; jj < 4; jj++)
          acc[ii][jj] += av[ii] * bv[jj];
    }
  }
  float4 g4 = *(const float4*)(g32 + col0 + tx * 4);
  float4 be = *(const float4*)(benc + col0 + tx * 4);
  float gv[4] = {g4.x, g4.y, g4.z, g4.w};
  float bev[4] = {be.x, be.y, be.z, be.w};
  unsigned thrBits = (MODE == 1) ? (unsigned)ctrl[1] : 0u;
#pragma unroll
  for (int ii = 0; ii < 4; ii++) {
#pragma unroll
    for (int jj = 0; jj < 4; jj++) {
      float z = acc[ii][jj] + bev[jj];
      float s = z > 0.f ? z * gv[jj] : 0.f;
      unsigned bits = __float_as_uint(s);
      if (MODE == 0) {
        if (bits) atomicAdd(&h[bits >> 21], 1);
      } else {
        bool pred = bits >= thrBits;
        int pos = wave_append(pred, &ctrl[2]);
        if (pred && pos < CAND_CAP) {
          cand_idx[pos] = (row0 + ty * 4 + ii) * D_SAE + (col0 + tx * 4 + jj);
          cand_sc[pos] = s;
        }
      }
    }
  }
  if (MODE == 0) {
    __syncthreads();
    for (int i = threadIdx.x; i < 2048; i += 256)
      if (h[i]) atomicAdd(&ghist[i], h[i]);
  }
}

// ---------- coarse bin threshold with margin ----------
__global__ void find_coarse_kernel(const int* __restrict__ gh, int* ctrl,
                                   const int* __restrict__ kptr) {
  if (threadIdx.x || blockIdx.x) return;
  int kB = kptr[0] * BATCH;
  long long cum = 0;
  int b = 2047;
  for (; b > 0; b--) {
    long long c = gh[b];
    if (cum + c >= kB) break;
    cum += c;
  }
  long long cumGE = cum + gh[b];
  if (cumGE - kB < COARSE_MARGIN && b > 0) b--;  // extend one bin lower for margin
  ctrl[0] = b;
  ctrl[1] = (int)(((unsigned)b) << 21);
}

// ---------- radix histograms over candidate scores ----------
__global__ __launch_bounds__(256) void chist_kernel(const float* __restrict__ cand_sc,
                                                    const int* __restrict__ ctrl,
                                                    int* __restrict__ ghist, int pass) {
  __shared__ int h[2048];
  int nb = (pass == 2) ? 1024 : 2048;
  for (int i = threadIdx.x; i < nb; i += 256) h[i] = 0;
  __syncthreads();
  int n = ctrl[2]; if (n > CAND_CAP) n = CAND_CAP;
  unsigned sel1 = 0, sel22 = 0;
  if (pass == 1) sel1 = (unsigned)ctrl[3];
  if (pass == 2) sel22 = ((unsigned)ctrl[3] << 11) | (unsigned)ctrl[5];
  for (int i = blockIdx.x * 256 + threadIdx.x; i < n; i += gridDim.x * 256) {
    unsigned bits = __float_as_uint(cand_sc[i]);
    if (pass == 0) atomicAdd(&h[bits >> 21], 1);
    else if (pass == 1) { if ((bits >> 21) == sel1) atomicAdd(&h[(bits >> 10) & 0x7FFu], 1); }
    else { if ((bits >> 10) == sel22) atomicAdd(&h[bits & 0x3FFu], 1); }
  }
  __syncthreads();
  for (int i = threadIdx.x; i < nb; i += 256)
    if (h[i]) atomicAdd(&ghist[i], h[i]);
}

__global__ void cfind_kernel(const int* __restrict__ hist, int* ctrl,
                             const int* __restrict__ kptr, int pass) {
  if (threadIdx.x || blockIdx.x) return;
  int kB = kptr[0] * BATCH;
  int need, nbins;
  if (pass == 0)      { need = kB;                       nbins = 2048; }
  else if (pass == 1) { need = kB - ctrl[4];             nbins = 2048; }
  else                { need = kB - ctrl[4] - ctrl[6];   nbins = 1024; }
  int cum = 0, b = nbins - 1;
  for (; b > 0; b--) {
    int c = hist[b];
    if (cum + c >= need) break;
    cum += c;
  }
  if (pass == 0)      { ctrl[3] = b; ctrl[4] = cum; }
  else if (pass == 1) { ctrl[5] = b; ctrl[6] = cum; }
  else {
    unsigned vbits = ((unsigned)ctrl[3] << 21) | ((unsigned)ctrl[5] << 10) | (unsigned)b;
    float V = __uint_as_float(vbits);
    float* cf = (float*)ctrl;
    cf[8] = V; cf[9] = V + EPS_M; cf[10] = V - EPS_M;
  }
}

// ---------- band partition: definite-in vs fp64-recheck candidates ----------
__global__ __launch_bounds__(256) void band_kernel(const int* __restrict__ cand_idx,
    const float* __restrict__ cand_sc, const float* __restrict__ g32,
    int* ctrl, int* row_cnt, int* row_feat, float* row_act, int* cand2_idx) {
  const float* cf = (const float*)ctrl;
  float hi = cf[9], lo = cf[10];
  int n = ctrl[2]; if (n > CAND_CAP) n = CAND_CAP;
  int lane = threadIdx.x & 63;
  int defc = 0;
  for (int i = blockIdx.x * 256 + threadIdx.x; i < n; i += gridDim.x * 256) {
    float s = cand_sc[i];
    int flat = cand_idx[i];
    if (s > hi) {
      int b = flat >> 14, j = flat & (D_SAE - 1);
      int p = atomicAdd(&row_cnt[b], 1);
      if (p < ROW_CAP) { row_feat[b * ROW_CAP + p] = j; row_act[b * ROW_CAP + p] = s / g32[j]; }
      defc++;
    }
    bool isc = (s <= hi) && (s >= lo);
    int pos = wave_append(isc, &ctrl[12]);
    if (isc && pos >= 0 && pos < CAND2_CAP) cand2_idx[pos] = flat;
  }
#pragma unroll
  for (int off = 32; off > 0; off >>= 1) defc += __shfl_down(defc, off, 64);
  if (lane == 0 && defc) atomicAdd(&ctrl[11], defc);
}

// ---------- fp64 rescore of band candidates (recompute LN per row) ----------
__global__ __launch_bounds__(256) void cand2_score_kernel(const int* __restrict__ ctrl,
    const int* __restrict__ cand2_idx, const float* __restrict__ x,
    const float* __restrict__ Wdec, const float* __restrict__ benc,
    const double* __restrict__ g64, double* __restrict__ cand2_sc) {
  __shared__ double lds[4];
  int n2 = ctrl[12]; if (n2 > CAND2_CAP) n2 = CAND2_CAP;
  int t = threadIdx.x;
  for (int c = blockIdx.x; c < n2; c += gridDim.x) {
    int flat = cand2_idx[c];
    int b = flat >> 14, j = flat & (D_SAE - 1);
    double d[4];
    ln_row_fp64(x + (size_t)b * (2 * D_MODEL), lds, d);
    float4 w4 = *(const float4*)(Wdec + (size_t)j * D_MODEL + t * 4);
    double a = d[0] * (double)w4.x + d[1] * (double)w4.y + d[2] * (double)w4.z + d[3] * (double)w4.w;
    double z = blockReduceSum256(a, lds) + (double)benc[j];
    double sc = z > 0 ? z * g64[j] : 0.0;
    if (t == 0) cand2_sc[c] = sc;
  }
}

// ---------- rank band candidates (fp64, index-stable), accept fill ----------
__global__ __launch_bounds__(256) void cand2_rank_kernel(const int* __restrict__ ctrl,
    const int* __restrict__ cand2_idx, const double* __restrict__ cand2_sc,
    const double* __restrict__ g64, const int* __restrict__ kptr,
    int* row_cnt, int* row_feat, float* row_act) {
  __shared__ int lds[4];
  int n2 = ctrl[12]; if (n2 > CAND2_CAP) n2 = CAND2_CAP;
  int kB = kptr[0] * BATCH;
  int fill = kB - ctrl[11];
  int t = threadIdx.x;
  for (int c = blockIdx.x; c < n2; c += gridDim.x) {
    double sc = cand2_sc[c];
    int fc = cand2_idx[c];
    int cnt = 0;
    for (int y = t; y < n2; y += 256) {
      double sy = cand2_sc[y];
      if (sy > sc || (sy == sc && cand2_idx[y] < fc)) cnt++;
    }
    cnt = blockReduceSumInt256(cnt, lds);
    if (t == 0 && cnt < fill) {
      int b = fc >> 14, j = fc & (D_SAE - 1);
      int p = atomicAdd(&row_cnt[b], 1);
      if (p < ROW_CAP) { row_feat[b * ROW_CAP + p] = j; row_act[b * ROW_CAP + p] = (float)(sc / g64[j]); }
    }
  }
}

// ---------- sparse recon ----------
__global__ __launch_bounds__(256) void recon_kernel(const int* __restrict__ row_cnt,
    const int* __restrict__ row_feat, const float* __restrict__ row_act,
    const float* __restrict__ Wdec, const float* __restrict__ bdec, float* __restrict__ out) {
  int b = blockIdx.x, t = threadIdx.x;
  float a0 = bdec[t], a1 = bdec[t + 256], a2 = bdec[t + 512], a3 = bdec[t + 768];
  int n = row_cnt[b]; if (n > ROW_CAP) n = ROW_CAP;
  const int* rf = row_feat + (size_t)b * ROW_CAP;
  const float* ra = row_act + (size_t)b * ROW_CAP;
  for (int p = 0; p < n; p++) {
    int j = rf[p]; float a = ra[p];
    const float* wr = Wdec + (size_t)j * D_MODEL;
    a0 += a * wr[t]; a1 += a * wr[t + 256]; a2 += a * wr[t + 512]; a3 += a * wr[t + 768];
  }
  float* o = out + (size_t)b * D_MODEL;
  o[t] = a0; o[t + 256] = a1; o[t + 512] = a2; o[t + 768] = a3;
}

extern "C" void kernel_launch(void* const* d_in, const int* in_sizes, int n_in,
                              void* d_out, int out_size, void* d_ws, size_t ws_size,
                              hipStream_t stream) {
  const float* x    = (const float*)d_in[0];
  const float* Wenc = (const float*)d_in[1];
  const float* benc = (const float*)d_in[2];
  const float* Wdec = (const float*)d_in[3];
  const float* bdec = (const float*)d_in[4];
  const int*   kptr = (const int*)d_in[5];
  float* out = (float*)d_out;

  char* ws = (char*)d_ws;
  size_t off = 0;
  float*  diff32    = (float*)(ws + off);  off += (size_t)BATCH * D_MODEL * 4;   // 16.8 MB
  int*    cand_idx  = (int*)(ws + off);    off += (size_t)CAND_CAP * 4;          // 16.8 MB
  float*  cand_sc   = (float*)(ws + off);  off += (size_t)CAND_CAP * 4;          // 16.8 MB
  int*    row_feat  = (int*)(ws + off);    off += (size_t)BATCH * ROW_CAP * 4;   // 4.2 MB
  float*  row_act   = (float*)(ws + off);  off += (size_t)BATCH * ROW_CAP * 4;   // 4.2 MB
  int*    cand2_idx = (int*)(ws + off);    off += (size_t)CAND2_CAP * 4;
  double* cand2_sc  = (double*)(ws + off); off += (size_t)CAND2_CAP * 8;
  double* g64       = (double*)(ws + off); off += (size_t)D_SAE * 8;
  float*  g32       = (float*)(ws + off);  off += (size_t)D_SAE * 4;
  char*   zbase     = ws + off;
  int* ghist   = (int*)(zbase);              // 2048
  int* h1      = (int*)(zbase + 8192);       // 2048
  int* h2      = (int*)(zbase + 16384);      // 2048
  int* h3      = (int*)(zbase + 24576);      // 1024
  int* ctrl    = (int*)(zbase + 28672);      // 64 ints
  int* row_cnt = (int*)(zbase + 28928);      // 4096 ints
  size_t zbytes = 28928 + (size_t)BATCH * 4;
  if (off + zbytes > ws_size) return;  // needs ~60 MB

  hipMemsetAsync(zbase, 0, zbytes, stream);

  ln_kernel<<<BATCH, 256, 0, stream>>>(x, diff32);
  norm_kernel<<<D_SAE, 256, 0, stream>>>(Wdec, g64, g32);
  dim3 gb(D_SAE / 64, BATCH / 64);
  gemm_kernel<0><<<gb, 256, 0, stream>>>(diff32, Wenc, benc, g32, ghist, ctrl, nullptr, nullptr);
  find_coarse_kernel<<<1, 1, 0, stream>>>(ghist, ctrl, kptr);
  gemm_kernel<1><<<gb, 256, 0, stream>>>(diff32, Wenc, benc, g32, nullptr, ctrl, cand_idx, cand_sc);
  chist_kernel<<<1024, 256, 0, stream>>>(cand_sc, ctrl, h1, 0);
  cfind_kernel<<<1, 1, 0, stream>>>(h1, ctrl, kptr, 0);
  chist_kernel<<<1024, 256, 0, stream>>>(cand_sc, ctrl, h2, 1);
  cfind_kernel<<<1, 1, 0, stream>>>(h2, ctrl, kptr, 1);
  chist_kernel<<<1024, 256, 0, stream>>>(cand_sc, ctrl, h3, 2);
  cfind_kernel<<<1, 1, 0, stream>>>(h3, ctrl, kptr, 2);
  band_kernel<<<1024, 256, 0, stream>>>(cand_idx, cand_sc, g32, ctrl, row_cnt, row_feat, row_act, cand2_idx);
  cand2_score_kernel<<<4096, 256, 0, stream>>>(ctrl, cand2_idx, x, Wdec, benc, g64, cand2_sc);
  cand2_rank_kernel<<<2048, 256, 0, stream>>>(ctrl, cand2_idx, cand2_sc, g64, kptr, row_cnt, row_feat, row_act);
  recon_kernel<<<BATCH, 256, 0, stream>>>(row_cnt, row_feat, row_act, Wdec, bdec, out);
}

// Round 4
// 5324.545 us; speedup vs baseline: 1.2876x; 1.2876x over previous
//
#include <hip/hip_runtime.h>
#include <math.h>

#define D_MODEL 1024
#define D_SAE   16384
#define BATCH   4096
#define NTOT    (1ull * BATCH * D_SAE)
#define LN_EPS  1e-8
#define EPS_M   1e-3f        // |split-bf16 score - fp64 score| safe band half-width
#define ROW_CAP 256
#define CAND_CAP  (4 * 1024 * 1024)
#define CAND2_CAP 65536
#define COARSE_MARGIN 32768

using bf16x8 = __attribute__((ext_vector_type(8))) short;
using f32x4  = __attribute__((ext_vector_type(4))) float;

__device__ inline unsigned short f2bf(float f) {   // RNE fp32->bf16
  unsigned u = __float_as_uint(f);
  return (unsigned short)((u + 0x7fffu + ((u >> 16) & 1u)) >> 16);
}
__device__ inline float bf2f(unsigned short h) {
  return __uint_as_float((unsigned)h << 16);
}

// ---------- block (256-thread) reductions ----------
__device__ inline double blockReduceSum256(double v, double* lds) {
#pragma unroll
  for (int off = 32; off > 0; off >>= 1) v += __shfl_down(v, off, 64);
  int lane = threadIdx.x & 63, wid = threadIdx.x >> 6;
  __syncthreads();
  if (lane == 0) lds[wid] = v;
  __syncthreads();
  return lds[0] + lds[1] + lds[2] + lds[3];
}
__device__ inline int blockReduceSumInt256(int v, int* lds) {
#pragma unroll
  for (int off = 32; off > 0; off >>= 1) v += __shfl_down(v, off, 64);
  int lane = threadIdx.x & 63, wid = threadIdx.x >> 6;
  __syncthreads();
  if (lane == 0) lds[wid] = v;
  __syncthreads();
  return lds[0] + lds[1] + lds[2] + lds[3];
}

__device__ inline int wave_append(bool pred, int* counter) {
  unsigned long long m = __ballot(pred);
  int lane = threadIdx.x & 63;
  int pos = -1;
  if (m) {
    int ldr = __ffsll((long long)m) - 1;
    int base = 0;
    if (lane == ldr) base = atomicAdd(counter, __popcll(m));
    base = __shfl(base, ldr, 64);
    if (pred) pos = base + __popcll(m & ((1ull << lane) - 1ull));
  }
  return pos;
}

// ---------- per-thread fp64 LN chain: thread t owns elements t*4..t*4+3 ----------
__device__ inline void ln_row_fp64(const float* __restrict__ row, double* lds, double d[4]) {
  int t = threadIdx.x;
  float4 s4 = *(const float4*)(row + t * 4);
  float4 t4 = *(const float4*)(row + D_MODEL + t * 4);
  double s[4] = {s4.x, s4.y, s4.z, s4.w};
  double tt[4] = {t4.x, t4.y, t4.z, t4.w};
  double ms = blockReduceSum256(s[0] + s[1] + s[2] + s[3], lds) / D_MODEL;
  double mt = blockReduceSum256(tt[0] + tt[1] + tt[2] + tt[3], lds) / D_MODEL;
  double vs = 0, vt = 0;
#pragma unroll
  for (int i = 0; i < 4; i++) { double a = s[i] - ms; vs += a * a; a = tt[i] - mt; vt += a * a; }
  vs = blockReduceSum256(vs, lds) / D_MODEL;
  vt = blockReduceSum256(vt, lds) / D_MODEL;
  double rs = sqrt(vs + LN_EPS), rt = sqrt(vt + LN_EPS);
  double u[4];
#pragma unroll
  for (int i = 0; i < 4; i++) u[i] = (tt[i] - mt) / rt - (s[i] - ms) / rs;
  double mu = blockReduceSum256(u[0] + u[1] + u[2] + u[3], lds) / D_MODEL;
  double vu = 0;
#pragma unroll
  for (int i = 0; i < 4; i++) { double a = u[i] - mu; vu += a * a; }
  vu = blockReduceSum256(vu, lds) / D_MODEL;
  double ru = sqrt(vu + LN_EPS);
#pragma unroll
  for (int i = 0; i < 4; i++) d[i] = (u[i] - mu) / ru;
}

// ---------- LN -> split-bf16 A in GEMM-tiled layout [mt][ks][kc][ml][e] ----------
__global__ __launch_bounds__(256) void ln_kernel(const float* __restrict__ x,
                                                 short* __restrict__ Ahi, short* __restrict__ Alo) {
  __shared__ double lds[4];
  int b = blockIdx.x, t = threadIdx.x;
  double d[4];
  ln_row_fp64(x + (size_t)b * (2 * D_MODEL), lds, d);
  int mt = b >> 7, ml = b & 127;
  int ks = t >> 3, kc = (t >> 1) & 3, e0 = (t & 1) * 4;
  size_t base = ((((size_t)mt * 32 + ks) * 4 + kc) * 128 + ml) * 8 + e0;
  short h[4], l[4];
#pragma unroll
  for (int i = 0; i < 4; i++) {
    float f = (float)d[i];
    unsigned short hh = f2bf(f);
    h[i] = (short)hh;
    l[i] = (short)f2bf(f - bf2f(hh));
  }
  *(short4*)&Ahi[base] = make_short4(h[0], h[1], h[2], h[3]);
  *(short4*)&Alo[base] = make_short4(l[0], l[1], l[2], l[3]);
}

// ---------- dec_norms in fp64 ----------
__global__ __launch_bounds__(256) void norm_kernel(const float* __restrict__ Wdec,
                                                   double* __restrict__ g64, float* __restrict__ g32) {
  __shared__ double lds[4];
  int j = blockIdx.x, t = threadIdx.x;
  float4 w = *(const float4*)(Wdec + (size_t)j * D_MODEL + t * 4);
  double a = (double)w.x * w.x + (double)w.y * w.y + (double)w.z * w.z + (double)w.w * w.w;
  double sum = blockReduceSum256(a, lds);
  if (t == 0) { double g = sqrt(sum); g64[j] = g; g32[j] = (float)g; }
}

// ---------- split-bf16 MFMA score GEMM: MODE 0 = histogram, MODE 1 = extract ----------
// 128x128 tile, BK=32, 4 waves (2x2 of 64x64), 16x16x32 bf16 MFMA, 3-term split.
template <int MODE>
__global__ __launch_bounds__(256) void mfma_gemm(
    const float* __restrict__ Wenc, const short* __restrict__ Ahi, const short* __restrict__ Alo,
    const float* __restrict__ benc, const float* __restrict__ g32,
    int* __restrict__ ghist, int* __restrict__ ctrl,
    int* __restrict__ cand_idx, float* __restrict__ cand_sc) {
  __shared__ short sA[8192];   // Ahi tile [4][128][8] | Alo tile
  __shared__ short sB[8192];   // Bhi tile [4][128][8] | Blo tile
  __shared__ int h[(MODE == 0) ? 2048 : 4];

  const int tid = threadIdx.x;
  const int lane = tid & 63;
  const int w = tid >> 6;
  const int wm = (w >> 1) * 64, wn = (w & 1) * 64;

  // XCD-aware swizzle over 4096 blocks (nwg%8==0)
  int lin = blockIdx.x;
  int swz = (lin & 7) * 512 + (lin >> 3);
  int mt = swz >> 7;          // 0..31
  int nt = swz & 127;         // 0..127
  const int row0 = mt * 128, col0 = nt * 128;

  if (MODE == 0) { for (int i = tid; i < 2048; i += 256) h[i] = 0; }

  const int nl = tid & 127;
  const int half = tid >> 7;  // 0,1
  const float* wbase = Wenc + (size_t)col0 + nl;
  const size_t atile = (size_t)mt * 131072;

  f32x4 acc[4][4] = {};
  const int kcl = lane >> 4, l15 = lane & 15;

  for (int ks = 0; ks < 32; ++ks) {
    const int k0 = ks * 32;
    // A tile loads (pre-split bf16, tiled-contiguous)
    const float4* ah4 = (const float4*)(Ahi + atile + ks * 4096);
    const float4* al4 = (const float4*)(Alo + atile + ks * 4096);
    float4 a0 = ah4[tid], a1 = ah4[tid + 256];
    float4 a2 = al4[tid], a3 = al4[tid + 256];
    // B loads (fp32 W_enc, coalesced across nl) + on-the-fly hi/lo split
    float bfv[16];
#pragma unroll
    for (int p = 0; p < 4; ++p)
#pragma unroll
      for (int i = 0; i < 4; ++i)
        bfv[p * 4 + i] = wbase[(size_t)(k0 + p * 8 + half * 4 + i) * D_SAE];
    short hb[16], lb[16];
#pragma unroll
    for (int j = 0; j < 16; ++j) {
      unsigned short hh = f2bf(bfv[j]);
      hb[j] = (short)hh;
      lb[j] = (short)f2bf(bfv[j] - bf2f(hh));
    }
    __syncthreads();   // previous tile fully consumed
    *(float4*)&sA[(size_t)tid * 8] = a0;
    *(float4*)&sA[(size_t)(tid + 256) * 8] = a1;
    *(float4*)&sA[(size_t)(512 + tid) * 8] = a2;
    *(float4*)&sA[(size_t)(512 + tid + 256) * 8] = a3;
#pragma unroll
    for (int p = 0; p < 4; ++p) {
      int boff = p * 1024 + nl * 8 + half * 4;
      *(short4*)&sB[boff] = make_short4(hb[p * 4], hb[p * 4 + 1], hb[p * 4 + 2], hb[p * 4 + 3]);
      *(short4*)&sB[4096 + boff] = make_short4(lb[p * 4], lb[p * 4 + 1], lb[p * 4 + 2], lb[p * 4 + 3]);
    }
    __syncthreads();   // tile visible
    // fragments + MFMA (A row=lane&15, k=(lane>>4)*8+e)
    bf16x8 ahf[4], alf[4];
#pragma unroll
    for (int fm = 0; fm < 4; ++fm) {
      int off = (kcl * 128 + wm + fm * 16 + l15) * 8;
      ahf[fm] = *(const bf16x8*)&sA[off];
      alf[fm] = *(const bf16x8*)&sA[4096 + off];
    }
#pragma unroll
    for (int fn = 0; fn < 4; ++fn) {
      int boff = (kcl * 128 + wn + fn * 16 + l15) * 8;
      bf16x8 bh = *(const bf16x8*)&sB[boff];
      bf16x8 bl = *(const bf16x8*)&sB[4096 + boff];
#pragma unroll
      for (int fm = 0; fm < 4; ++fm) {
        acc[fm][fn] = __builtin_amdgcn_mfma_f32_16x16x32_bf16(ahf[fm], bh, acc[fm][fn], 0, 0, 0);
        acc[fm][fn] = __builtin_amdgcn_mfma_f32_16x16x32_bf16(alf[fm], bh, acc[fm][fn], 0, 0, 0);
        acc[fm][fn] = __builtin_amdgcn_mfma_f32_16x16x32_bf16(ahf[fm], bl, acc[fm][fn], 0, 0, 0);
      }
    }
  }

  // epilogue: C col=lane&15, row=(lane>>4)*4+r (m89-verified)
  unsigned thrBits = (MODE == 1) ? (unsigned)ctrl[1] : 0u;
  const int l4r = lane >> 4;
#pragma unroll
  for (int fn = 0; fn < 4; ++fn) {
    int col = col0 + wn + fn * 16 + l15;
    float g = g32[col], be = benc[col];
#pragma unroll
    for (int fm = 0; fm < 4; ++fm) {
      int rowb = row0 + wm + fm * 16 + l4r * 4;
#pragma unroll
      for (int r = 0; r < 4; ++r) {
        float z = acc[fm][fn][r] + be;
        float s = z > 0.f ? z * g : 0.f;
        unsigned bits = __float_as_uint(s);
        if (MODE == 0) {
          if (bits) atomicAdd(&h[bits >> 21], 1);
        } else {
          bool pred = bits >= thrBits;
          int pos = wave_append(pred, &ctrl[2]);
          if (pred && pos >= 0 && pos < CAND_CAP) {
            cand_idx[pos] = (rowb + r) * D_SAE + col;
            cand_sc[pos] = s;
          }
        }
      }
    }
  }
  if (MODE == 0) {
    __syncthreads();
    for (int i = tid; i < 2048; i += 256)
      if (h[i]) atomicAdd(&ghist[i], h[i]);
  }
}

// ---------- coarse bin threshold with margin ----------
__global__ void find_coarse_kernel(const int* __restrict__ gh, int* ctrl,
                                   const int* __restrict__ kptr) {
  if (threadIdx.x || blockIdx.x) return;
  int kB = kptr[0] * BATCH;
  long long cum = 0;
  int b = 2047;
  for (; b > 0; b--) {
    long long c = gh[b];
    if (cum + c >= kB) break;
    cum += c;
  }
  long long cumGE = cum + gh[b];
  if (cumGE - kB < COARSE_MARGIN && b > 0) b--;
  ctrl[0] = b;
  ctrl[1] = (int)(((unsigned)b) << 21);
}

// ---------- radix histograms over candidate scores ----------
__global__ __launch_bounds__(256) void chist_kernel(const float* __restrict__ cand_sc,
                                                    const int* __restrict__ ctrl,
                                                    int* __restrict__ ghist, int pass) {
  __shared__ int h[2048];
  int nb = (pass == 2) ? 1024 : 2048;
  for (int i = threadIdx.x; i < nb; i += 256) h[i] = 0;
  __syncthreads();
  int n = ctrl[2]; if (n > CAND_CAP) n = CAND_CAP;
  unsigned sel1 = 0, sel22 = 0;
  if (pass == 1) sel1 = (unsigned)ctrl[3];
  if (pass == 2) sel22 = ((unsigned)ctrl[3] << 11) | (unsigned)ctrl[5];
  for (int i = blockIdx.x * 256 + threadIdx.x; i < n; i += gridDim.x * 256) {
    unsigned bits = __float_as_uint(cand_sc[i]);
    if (pass == 0) atomicAdd(&h[bits >> 21], 1);
    else if (pass == 1) { if ((bits >> 21) == sel1) atomicAdd(&h[(bits >> 10) & 0x7FFu], 1); }
    else { if ((bits >> 10) == sel22) atomicAdd(&h[bits & 0x3FFu], 1); }
  }
  __syncthreads();
  for (int i = threadIdx.x; i < nb; i += 256)
    if (h[i]) atomicAdd(&ghist[i], h[i]);
}

__global__ void cfind_kernel(const int* __restrict__ hist, int* ctrl,
                             const int* __restrict__ kptr, int pass) {
  if (threadIdx.x || blockIdx.x) return;
  int kB = kptr[0] * BATCH;
  int need, nbins;
  if (pass == 0)      { need = kB;                       nbins = 2048; }
  else if (pass == 1) { need = kB - ctrl[4];             nbins = 2048; }
  else                { need = kB - ctrl[4] - ctrl[6];   nbins = 1024; }
  int cum = 0, b = nbins - 1;
  for (; b > 0; b--) {
    int c = hist[b];
    if (cum + c >= need) break;
    cum += c;
  }
  if (pass == 0)      { ctrl[3] = b; ctrl[4] = cum; }
  else if (pass == 1) { ctrl[5] = b; ctrl[6] = cum; }
  else {
    unsigned vbits = ((unsigned)ctrl[3] << 21) | ((unsigned)ctrl[5] << 10) | (unsigned)b;
    float V = __uint_as_float(vbits);
    float* cf = (float*)ctrl;
    cf[8] = V; cf[9] = V + EPS_M; cf[10] = V - EPS_M;
  }
}

// ---------- band partition ----------
__global__ __launch_bounds__(256) void band_kernel(const int* __restrict__ cand_idx,
    const float* __restrict__ cand_sc, const float* __restrict__ g32,
    int* ctrl, int* row_cnt, int* row_feat, float* row_act, int* cand2_idx) {
  const float* cf = (const float*)ctrl;
  float hi = cf[9], lo = cf[10];
  int n = ctrl[2]; if (n > CAND_CAP) n = CAND_CAP;
  int lane = threadIdx.x & 63;
  int defc = 0;
  for (int i = blockIdx.x * 256 + threadIdx.x; i < n; i += gridDim.x * 256) {
    float s = cand_sc[i];
    int flat = cand_idx[i];
    if (s > hi) {
      int b = flat >> 14, j = flat & (D_SAE - 1);
      int p = atomicAdd(&row_cnt[b], 1);
      if (p < ROW_CAP) { row_feat[b * ROW_CAP + p] = j; row_act[b * ROW_CAP + p] = s / g32[j]; }
      defc++;
    }
    bool isc = (s <= hi) && (s >= lo);
    int pos = wave_append(isc, &ctrl[12]);
    if (isc && pos >= 0 && pos < CAND2_CAP) cand2_idx[pos] = flat;
  }
#pragma unroll
  for (int off = 32; off > 0; off >>= 1) defc += __shfl_down(defc, off, 64);
  if (lane == 0 && defc) atomicAdd(&ctrl[11], defc);
}

// ---------- fp64 rescore of band candidates ----------
__global__ __launch_bounds__(256) void cand2_score_kernel(const int* __restrict__ ctrl,
    const int* __restrict__ cand2_idx, const float* __restrict__ x,
    const float* __restrict__ Wdec, const float* __restrict__ benc,
    const double* __restrict__ g64, double* __restrict__ cand2_sc) {
  __shared__ double lds[4];
  int n2 = ctrl[12]; if (n2 > CAND2_CAP) n2 = CAND2_CAP;
  int t = threadIdx.x;
  for (int c = blockIdx.x; c < n2; c += gridDim.x) {
    int flat = cand2_idx[c];
    int b = flat >> 14, j = flat & (D_SAE - 1);
    double d[4];
    ln_row_fp64(x + (size_t)b * (2 * D_MODEL), lds, d);
    float4 w4 = *(const float4*)(Wdec + (size_t)j * D_MODEL + t * 4);
    double a = d[0] * (double)w4.x + d[1] * (double)w4.y + d[2] * (double)w4.z + d[3] * (double)w4.w;
    double z = blockReduceSum256(a, lds) + (double)benc[j];
    double sc = z > 0 ? z * g64[j] : 0.0;
    if (t == 0) cand2_sc[c] = sc;
  }
}

// ---------- rank band candidates (fp64, index-stable), accept fill ----------
__global__ __launch_bounds__(256) void cand2_rank_kernel(const int* __restrict__ ctrl,
    const int* __restrict__ cand2_idx, const double* __restrict__ cand2_sc,
    const double* __restrict__ g64, const int* __restrict__ kptr,
    int* row_cnt, int* row_feat, float* row_act) {
  __shared__ int lds[4];
  int n2 = ctrl[12]; if (n2 > CAND2_CAP) n2 = CAND2_CAP;
  int kB = kptr[0] * BATCH;
  int fill = kB - ctrl[11];
  int t = threadIdx.x;
  for (int c = blockIdx.x; c < n2; c += gridDim.x) {
    double sc = cand2_sc[c];
    int fc = cand2_idx[c];
    int cnt = 0;
    for (int y = t; y < n2; y += 256) {
      double sy = cand2_sc[y];
      if (sy > sc || (sy == sc && cand2_idx[y] < fc)) cnt++;
    }
    cnt = blockReduceSumInt256(cnt, lds);
    if (t == 0 && cnt < fill) {
      int b = fc >> 14, j = fc & (D_SAE - 1);
      int p = atomicAdd(&row_cnt[b], 1);
      if (p < ROW_CAP) { row_feat[b * ROW_CAP + p] = j; row_act[b * ROW_CAP + p] = (float)(sc / g64[j]); }
    }
  }
}

// ---------- sparse recon ----------
__global__ __launch_bounds__(256) void recon_kernel(const int* __restrict__ row_cnt,
    const int* __restrict__ row_feat, const float* __restrict__ row_act,
    const float* __restrict__ Wdec, const float* __restrict__ bdec, float* __restrict__ out) {
  int b = blockIdx.x, t = threadIdx.x;
  float a0 = bdec[t], a1 = bdec[t + 256], a2 = bdec[t + 512], a3 = bdec[t + 768];
  int n = row_cnt[b]; if (n > ROW_CAP) n = ROW_CAP;
  const int* rf = row_feat + (size_t)b * ROW_CAP;
  const float* ra = row_act + (size_t)b * ROW_CAP;
  for (int p = 0; p < n; p++) {
    int j = rf[p]; float a = ra[p];
    const float* wr = Wdec + (size_t)j * D_MODEL;
    a0 += a * wr[t]; a1 += a * wr[t + 256]; a2 += a * wr[t + 512]; a3 += a * wr[t + 768];
  }
  float* o = out + (size_t)b * D_MODEL;
  o[t] = a0; o[t + 256] = a1; o[t + 512] = a2; o[t + 768] = a3;
}

extern "C" void kernel_launch(void* const* d_in, const int* in_sizes, int n_in,
                              void* d_out, int out_size, void* d_ws, size_t ws_size,
                              hipStream_t stream) {
  const float* x    = (const float*)d_in[0];
  const float* Wenc = (const float*)d_in[1];
  const float* benc = (const float*)d_in[2];
  const float* Wdec = (const float*)d_in[3];
  const float* bdec = (const float*)d_in[4];
  const int*   kptr = (const int*)d_in[5];
  float* out = (float*)d_out;

  char* ws = (char*)d_ws;
  size_t off = 0;
  short*  Ahi       = (short*)(ws + off);  off += (size_t)BATCH * D_MODEL * 2;   // 8.4 MB
  short*  Alo       = (short*)(ws + off);  off += (size_t)BATCH * D_MODEL * 2;   // 8.4 MB
  int*    cand_idx  = (int*)(ws + off);    off += (size_t)CAND_CAP * 4;          // 16.8 MB
  float*  cand_sc   = (float*)(ws + off);  off += (size_t)CAND_CAP * 4;          // 16.8 MB
  int*    row_feat  = (int*)(ws + off);    off += (size_t)BATCH * ROW_CAP * 4;   // 4.2 MB
  float*  row_act   = (float*)(ws + off);  off += (size_t)BATCH * ROW_CAP * 4;   // 4.2 MB
  int*    cand2_idx = (int*)(ws + off);    off += (size_t)CAND2_CAP * 4;
  double* cand2_sc  = (double*)(ws + off); off += (size_t)CAND2_CAP * 8;
  double* g64       = (double*)(ws + off); off += (size_t)D_SAE * 8;
  float*  g32       = (float*)(ws + off);  off += (size_t)D_SAE * 4;
  char*   zbase     = ws + off;
  int* ghist   = (int*)(zbase);
  int* h1      = (int*)(zbase + 8192);
  int* h2      = (int*)(zbase + 16384);
  int* h3      = (int*)(zbase + 24576);
  int* ctrl    = (int*)(zbase + 28672);
  int* row_cnt = (int*)(zbase + 28928);
  size_t zbytes = 28928 + (size_t)BATCH * 4;
  if (off + zbytes > ws_size) return;  // needs ~60 MB (round-2-proven size)

  hipMemsetAsync(zbase, 0, zbytes, stream);

  ln_kernel<<<BATCH, 256, 0, stream>>>(x, Ahi, Alo);
  norm_kernel<<<D_SAE, 256, 0, stream>>>(Wdec, g64, g32);
  mfma_gemm<0><<<4096, 256, 0, stream>>>(Wenc, Ahi, Alo, benc, g32, ghist, ctrl, nullptr, nullptr);
  find_coarse_kernel<<<1, 1, 0, stream>>>(ghist, ctrl, kptr);
  mfma_gemm<1><<<4096, 256, 0, stream>>>(Wenc, Ahi, Alo, benc, g32, nullptr, ctrl, cand_idx, cand_sc);
  chist_kernel<<<1024, 256, 0, stream>>>(cand_sc, ctrl, h1, 0);
  cfind_kernel<<<1, 1, 0, stream>>>(h1, ctrl, kptr, 0);
  chist_kernel<<<1024, 256, 0, stream>>>(cand_sc, ctrl, h2, 1);
  cfind_kernel<<<1, 1, 0, stream>>>(h2, ctrl, kptr, 1);
  chist_kernel<<<1024, 256, 0, stream>>>(cand_sc, ctrl, h3, 2);
  cfind_kernel<<<1, 1, 0, stream>>>(h3, ctrl, kptr, 2);
  band_kernel<<<1024, 256, 0, stream>>>(cand_idx, cand_sc, g32, ctrl, row_cnt, row_feat, row_act, cand2_idx);
  cand2_score_kernel<<<4096, 256, 0, stream>>>(ctrl, cand2_idx, x, Wdec, benc, g64, cand2_sc);
  cand2_rank_kernel<<<2048, 256, 0, stream>>>(ctrl, cand2_idx, cand2_sc, g64, kptr, row_cnt, row_feat, row_act);
  recon_kernel<<<BATCH, 256, 0, stream>>>(row_cnt, row_feat, row_act, Wdec, bdec, out);
}

// Round 5
// 1714.009 us; speedup vs baseline: 3.9998x; 3.1065x over previous
//
#include <hip/hip_runtime.h>
#include <math.h>

#define D_MODEL 1024
#define D_SAE   16384
#define BATCH   4096
#define NTOT    (1ull * BATCH * D_SAE)
#define LN_EPS  1e-8
#define EPS_M   1e-3f        // |split-bf16 score - fp64 score| safe band half-width
#define ROW_CAP 256
#define CAND_CAP  (4 * 1024 * 1024)
#define CAND2_CAP 65536
#define COARSE_MARGIN 32768

using bf16x8 = __attribute__((ext_vector_type(8))) short;
using f32x4  = __attribute__((ext_vector_type(4))) float;

__device__ inline unsigned short f2bf(float f) {   // RNE fp32->bf16
  unsigned u = __float_as_uint(f);
  return (unsigned short)((u + 0x7fffu + ((u >> 16) & 1u)) >> 16);
}
__device__ inline float bf2f(unsigned short h) {
  return __uint_as_float((unsigned)h << 16);
}

// ---------- block (256-thread) reductions ----------
__device__ inline double blockReduceSum256(double v, double* lds) {
#pragma unroll
  for (int off = 32; off > 0; off >>= 1) v += __shfl_down(v, off, 64);
  int lane = threadIdx.x & 63, wid = threadIdx.x >> 6;
  __syncthreads();
  if (lane == 0) lds[wid] = v;
  __syncthreads();
  return lds[0] + lds[1] + lds[2] + lds[3];
}
__device__ inline int blockReduceSumInt256(int v, int* lds) {
#pragma unroll
  for (int off = 32; off > 0; off >>= 1) v += __shfl_down(v, off, 64);
  int lane = threadIdx.x & 63, wid = threadIdx.x >> 6;
  __syncthreads();
  if (lane == 0) lds[wid] = v;
  __syncthreads();
  return lds[0] + lds[1] + lds[2] + lds[3];
}

__device__ inline int wave_append(bool pred, int* counter) {
  unsigned long long m = __ballot(pred);
  int lane = threadIdx.x & 63;
  int pos = -1;
  if (m) {
    int ldr = __ffsll((long long)m) - 1;
    int base = 0;
    if (lane == ldr) base = atomicAdd(counter, __popcll(m));
    base = __shfl(base, ldr, 64);
    if (pred) pos = base + __popcll(m & ((1ull << lane) - 1ull));
  }
  return pos;
}

// ---------- per-thread fp64 LN chain: thread t owns elements t*4..t*4+3 ----------
__device__ inline void ln_row_fp64(const float* __restrict__ row, double* lds, double d[4]) {
  int t = threadIdx.x;
  float4 s4 = *(const float4*)(row + t * 4);
  float4 t4 = *(const float4*)(row + D_MODEL + t * 4);
  double s[4] = {s4.x, s4.y, s4.z, s4.w};
  double tt[4] = {t4.x, t4.y, t4.z, t4.w};
  double ms = blockReduceSum256(s[0] + s[1] + s[2] + s[3], lds) / D_MODEL;
  double mt = blockReduceSum256(tt[0] + tt[1] + tt[2] + tt[3], lds) / D_MODEL;
  double vs = 0, vt = 0;
#pragma unroll
  for (int i = 0; i < 4; i++) { double a = s[i] - ms; vs += a * a; a = tt[i] - mt; vt += a * a; }
  vs = blockReduceSum256(vs, lds) / D_MODEL;
  vt = blockReduceSum256(vt, lds) / D_MODEL;
  double rs = sqrt(vs + LN_EPS), rt = sqrt(vt + LN_EPS);
  double u[4];
#pragma unroll
  for (int i = 0; i < 4; i++) u[i] = (tt[i] - mt) / rt - (s[i] - ms) / rs;
  double mu = blockReduceSum256(u[0] + u[1] + u[2] + u[3], lds) / D_MODEL;
  double vu = 0;
#pragma unroll
  for (int i = 0; i < 4; i++) { double a = u[i] - mu; vu += a * a; }
  vu = blockReduceSum256(vu, lds) / D_MODEL;
  double ru = sqrt(vu + LN_EPS);
#pragma unroll
  for (int i = 0; i < 4; i++) d[i] = (u[i] - mu) / ru;
}

// ---------- LN -> split-bf16 A in GEMM-tiled layout [mt][ks][kc][ml][e] ----------
__global__ __launch_bounds__(256) void ln_kernel(const float* __restrict__ x,
                                                 short* __restrict__ Ahi, short* __restrict__ Alo) {
  __shared__ double lds[4];
  int b = blockIdx.x, t = threadIdx.x;
  double d[4];
  ln_row_fp64(x + (size_t)b * (2 * D_MODEL), lds, d);
  int mt = b >> 7, ml = b & 127;
  int ks = t >> 3, kc = (t >> 1) & 3, e0 = (t & 1) * 4;
  size_t base = ((((size_t)mt * 32 + ks) * 4 + kc) * 128 + ml) * 8 + e0;
  short h[4], l[4];
#pragma unroll
  for (int i = 0; i < 4; i++) {
    float f = (float)d[i];
    unsigned short hh = f2bf(f);
    h[i] = (short)hh;
    l[i] = (short)f2bf(f - bf2f(hh));
  }
  *(short4*)&Ahi[base] = make_short4(h[0], h[1], h[2], h[3]);
  *(short4*)&Alo[base] = make_short4(l[0], l[1], l[2], l[3]);
}

// ---------- dec_norms in fp64 ----------
__global__ __launch_bounds__(256) void norm_kernel(const float* __restrict__ Wdec,
                                                   double* __restrict__ g64, float* __restrict__ g32) {
  __shared__ double lds[4];
  int j = blockIdx.x, t = threadIdx.x;
  float4 w = *(const float4*)(Wdec + (size_t)j * D_MODEL + t * 4);
  double a = (double)w.x * w.x + (double)w.y * w.y + (double)w.z * w.z + (double)w.w * w.w;
  double sum = blockReduceSum256(a, lds);
  if (t == 0) { double g = sqrt(sum); g64[j] = g; g32[j] = (float)g; }
}

// ---------- split-bf16 MFMA score GEMM: MODE 0 = histogram, MODE 1 = extract ----------
// 128x128 tile, BK=32, 4 waves, 16x16x32 bf16 MFMA, 3-term split.
// L2-locality mapping + register prefetch pipeline + block-aggregated append.
template <int MODE>
__global__ __launch_bounds__(256) void mfma_gemm(
    const float* __restrict__ Wenc, const short* __restrict__ Ahi, const short* __restrict__ Alo,
    const float* __restrict__ benc, const float* __restrict__ g32,
    int* __restrict__ ghist, int* __restrict__ ctrl,
    int* __restrict__ cand_idx, float* __restrict__ cand_sc) {
  __shared__ short sA[8192];   // Ahi tile [4][128][8] | Alo tile
  __shared__ short sB[8192];   // Bhi tile [4][128][8] | Blo tile
  __shared__ int h[(MODE == 0) ? 2048 : 2];

  const int tid = threadIdx.x;
  const int lane = tid & 63;
  const int w = tid >> 6;
  const int wm = (w >> 1) * 64, wn = (w & 1) * 64;

  // L2-locality mapping: XCD x = lin&7 owns nt in [16x,16x+16); within an XCD,
  // 32 consecutive blocks (j = lin>>3) share one 512KB B panel (same nt, mt 0..31)
  // -> B fetched once per XCD; XCD column slices disjoint -> B HBM = 64MB total.
  int lin = blockIdx.x;
  int xcd = lin & 7, j = lin >> 3;
  int mt = j & 31;
  int nt = (xcd << 4) | (j >> 5);
  const int row0 = mt * 128, col0 = nt * 128;

  if (MODE == 0) { for (int i = tid; i < 2048; i += 256) h[i] = 0; }
  else if (tid == 0) h[0] = 0;

  const int nl = tid & 127;
  const int half = tid >> 7;  // 0,1
  const float* wbase = Wenc + (size_t)col0 + nl;
  const size_t atile = (size_t)mt * 131072;

  f32x4 acc[4][4] = {};
  const int kcl = lane >> 4, l15 = lane & 15;

  // ---- prologue: load tile 0 into registers ----
  float4 a0, a1, a2, a3;
  float bfv[16];
  {
    const float4* ah4 = (const float4*)(Ahi + atile);
    const float4* al4 = (const float4*)(Alo + atile);
    a0 = ah4[tid]; a1 = ah4[tid + 256];
    a2 = al4[tid]; a3 = al4[tid + 256];
#pragma unroll
    for (int p = 0; p < 4; ++p)
#pragma unroll
      for (int i = 0; i < 4; ++i)
        bfv[p * 4 + i] = wbase[(size_t)(p * 8 + half * 4 + i) * D_SAE];
  }

  for (int ks = 0; ks < 32; ++ks) {
    // convert the in-register B slice (from tile ks) to hi/lo bf16
    short hb[16], lb[16];
#pragma unroll
    for (int q = 0; q < 16; ++q) {
      unsigned short hh = f2bf(bfv[q]);
      hb[q] = (short)hh;
      lb[q] = (short)f2bf(bfv[q] - bf2f(hh));
    }
    __syncthreads();   // previous tile fully consumed
    *(float4*)&sA[(size_t)tid * 8] = a0;
    *(float4*)&sA[(size_t)(tid + 256) * 8] = a1;
    *(float4*)&sA[(size_t)(512 + tid) * 8] = a2;
    *(float4*)&sA[(size_t)(512 + tid + 256) * 8] = a3;
#pragma unroll
    for (int p = 0; p < 4; ++p) {
      int boff = p * 1024 + nl * 8 + half * 4;
      *(short4*)&sB[boff] = make_short4(hb[p * 4], hb[p * 4 + 1], hb[p * 4 + 2], hb[p * 4 + 3]);
      *(short4*)&sB[4096 + boff] = make_short4(lb[p * 4], lb[p * 4 + 1], lb[p * 4 + 2], lb[p * 4 + 3]);
    }
    __syncthreads();   // tile visible

    // ---- prefetch tile ks+1 into registers; latency hides under MFMA below ----
    if (ks < 31) {
      const int k0n = (ks + 1) * 32;
      const float4* ah4 = (const float4*)(Ahi + atile + (ks + 1) * 4096);
      const float4* al4 = (const float4*)(Alo + atile + (ks + 1) * 4096);
      a0 = ah4[tid]; a1 = ah4[tid + 256];
      a2 = al4[tid]; a3 = al4[tid + 256];
#pragma unroll
      for (int p = 0; p < 4; ++p)
#pragma unroll
        for (int i = 0; i < 4; ++i)
          bfv[p * 4 + i] = wbase[(size_t)(k0n + p * 8 + half * 4 + i) * D_SAE];
    }

    // fragments + MFMA (A row=lane&15, k=(lane>>4)*8+e)
    bf16x8 ahf[4], alf[4];
#pragma unroll
    for (int fm = 0; fm < 4; ++fm) {
      int off = (kcl * 128 + wm + fm * 16 + l15) * 8;
      ahf[fm] = *(const bf16x8*)&sA[off];
      alf[fm] = *(const bf16x8*)&sA[4096 + off];
    }
#pragma unroll
    for (int fn = 0; fn < 4; ++fn) {
      int boff = (kcl * 128 + wn + fn * 16 + l15) * 8;
      bf16x8 bh = *(const bf16x8*)&sB[boff];
      bf16x8 bl = *(const bf16x8*)&sB[4096 + boff];
#pragma unroll
      for (int fm = 0; fm < 4; ++fm) {
        acc[fm][fn] = __builtin_amdgcn_mfma_f32_16x16x32_bf16(ahf[fm], bh, acc[fm][fn], 0, 0, 0);
        acc[fm][fn] = __builtin_amdgcn_mfma_f32_16x16x32_bf16(alf[fm], bh, acc[fm][fn], 0, 0, 0);
        acc[fm][fn] = __builtin_amdgcn_mfma_f32_16x16x32_bf16(ahf[fm], bl, acc[fm][fn], 0, 0, 0);
      }
    }
  }

  // epilogue: C col=lane&15, row=(lane>>4)*4+r (m89-verified)
  const int l4r = lane >> 4;
  if (MODE == 0) {
#pragma unroll
    for (int fn = 0; fn < 4; ++fn) {
      int col = col0 + wn + fn * 16 + l15;
      float g = g32[col], be = benc[col];
#pragma unroll
      for (int fm = 0; fm < 4; ++fm) {
#pragma unroll
        for (int r = 0; r < 4; ++r) {
          float z = acc[fm][fn][r] + be;
          float s = z > 0.f ? z * g : 0.f;
          unsigned bits = __float_as_uint(s);
          if (bits) atomicAdd(&h[bits >> 21], 1);
        }
      }
    }
    __syncthreads();
    for (int i = tid; i < 2048; i += 256)
      if (h[i]) atomicAdd(&ghist[i], h[i]);
  } else {
    // block-aggregated append: count -> LDS prefix -> one global atomic -> write
    unsigned thrBits = (unsigned)ctrl[1];
    int cnt = 0;
#pragma unroll
    for (int fn = 0; fn < 4; ++fn) {
      int col = col0 + wn + fn * 16 + l15;
      float g = g32[col], be = benc[col];
#pragma unroll
      for (int fm = 0; fm < 4; ++fm) {
#pragma unroll
        for (int r = 0; r < 4; ++r) {
          float z = acc[fm][fn][r] + be;
          float s = z > 0.f ? z * g : 0.f;
          cnt += (__float_as_uint(s) >= thrBits) ? 1 : 0;
        }
      }
    }
    int my = 0;
    if (cnt) my = atomicAdd(&h[0], cnt);
    __syncthreads();
    if (tid == 0) h[1] = atomicAdd(&ctrl[2], h[0]);
    __syncthreads();
    int pos = h[1] + my;
#pragma unroll
    for (int fn = 0; fn < 4; ++fn) {
      int col = col0 + wn + fn * 16 + l15;
      float g = g32[col], be = benc[col];
#pragma unroll
      for (int fm = 0; fm < 4; ++fm) {
        int rowb = row0 + wm + fm * 16 + l4r * 4;
#pragma unroll
        for (int r = 0; r < 4; ++r) {
          float z = acc[fm][fn][r] + be;
          float s = z > 0.f ? z * g : 0.f;
          if (__float_as_uint(s) >= thrBits) {
            if (pos < CAND_CAP) { cand_idx[pos] = (rowb + r) * D_SAE + col; cand_sc[pos] = s; }
            pos++;
          }
        }
      }
    }
  }
}

// ---------- coarse bin threshold with margin ----------
__global__ void find_coarse_kernel(const int* __restrict__ gh, int* ctrl,
                                   const int* __restrict__ kptr) {
  if (threadIdx.x || blockIdx.x) return;
  int kB = kptr[0] * BATCH;
  long long cum = 0;
  int b = 2047;
  for (; b > 0; b--) {
    long long c = gh[b];
    if (cum + c >= kB) break;
    cum += c;
  }
  long long cumGE = cum + gh[b];
  if (cumGE - kB < COARSE_MARGIN && b > 0) b--;
  ctrl[0] = b;
  ctrl[1] = (int)(((unsigned)b) << 21);
}

// ---------- radix histograms over candidate scores ----------
__global__ __launch_bounds__(256) void chist_kernel(const float* __restrict__ cand_sc,
                                                    const int* __restrict__ ctrl,
                                                    int* __restrict__ ghist, int pass) {
  __shared__ int h[2048];
  int nb = (pass == 2) ? 1024 : 2048;
  for (int i = threadIdx.x; i < nb; i += 256) h[i] = 0;
  __syncthreads();
  int n = ctrl[2]; if (n > CAND_CAP) n = CAND_CAP;
  unsigned sel1 = 0, sel22 = 0;
  if (pass == 1) sel1 = (unsigned)ctrl[3];
  if (pass == 2) sel22 = ((unsigned)ctrl[3] << 11) | (unsigned)ctrl[5];
  for (int i = blockIdx.x * 256 + threadIdx.x; i < n; i += gridDim.x * 256) {
    unsigned bits = __float_as_uint(cand_sc[i]);
    if (pass == 0) atomicAdd(&h[bits >> 21], 1);
    else if (pass == 1) { if ((bits >> 21) == sel1) atomicAdd(&h[(bits >> 10) & 0x7FFu], 1); }
    else { if ((bits >> 10) == sel22) atomicAdd(&h[bits & 0x3FFu], 1); }
  }
  __syncthreads();
  for (int i = threadIdx.x; i < nb; i += 256)
    if (h[i]) atomicAdd(&ghist[i], h[i]);
}

__global__ void cfind_kernel(const int* __restrict__ hist, int* ctrl,
                             const int* __restrict__ kptr, int pass) {
  if (threadIdx.x || blockIdx.x) return;
  int kB = kptr[0] * BATCH;
  int need, nbins;
  if (pass == 0)      { need = kB;                       nbins = 2048; }
  else if (pass == 1) { need = kB - ctrl[4];             nbins = 2048; }
  else                { need = kB - ctrl[4] - ctrl[6];   nbins = 1024; }
  int cum = 0, b = nbins - 1;
  for (; b > 0; b--) {
    int c = hist[b];
    if (cum + c >= need) break;
    cum += c;
  }
  if (pass == 0)      { ctrl[3] = b; ctrl[4] = cum; }
  else if (pass == 1) { ctrl[5] = b; ctrl[6] = cum; }
  else {
    unsigned vbits = ((unsigned)ctrl[3] << 21) | ((unsigned)ctrl[5] << 10) | (unsigned)b;
    float V = __uint_as_float(vbits);
    float* cf = (float*)ctrl;
    cf[8] = V; cf[9] = V + EPS_M; cf[10] = V - EPS_M;
  }
}

// ---------- band partition ----------
__global__ __launch_bounds__(256) void band_kernel(const int* __restrict__ cand_idx,
    const float* __restrict__ cand_sc, const float* __restrict__ g32,
    int* ctrl, int* row_cnt, int* row_feat, float* row_act, int* cand2_idx) {
  const float* cf = (const float*)ctrl;
  float hi = cf[9], lo = cf[10];
  int n = ctrl[2]; if (n > CAND_CAP) n = CAND_CAP;
  int lane = threadIdx.x & 63;
  int defc = 0;
  for (int i = blockIdx.x * 256 + threadIdx.x; i < n; i += gridDim.x * 256) {
    float s = cand_sc[i];
    int flat = cand_idx[i];
    if (s > hi) {
      int b = flat >> 14, j = flat & (D_SAE - 1);
      int p = atomicAdd(&row_cnt[b], 1);
      if (p < ROW_CAP) { row_feat[b * ROW_CAP + p] = j; row_act[b * ROW_CAP + p] = s / g32[j]; }
      defc++;
    }
    bool isc = (s <= hi) && (s >= lo);
    int pos = wave_append(isc, &ctrl[12]);
    if (isc && pos >= 0 && pos < CAND2_CAP) cand2_idx[pos] = flat;
  }
#pragma unroll
  for (int off = 32; off > 0; off >>= 1) defc += __shfl_down(defc, off, 64);
  if (lane == 0 && defc) atomicAdd(&ctrl[11], defc);
}

// ---------- fp64 rescore of band candidates ----------
__global__ __launch_bounds__(256) void cand2_score_kernel(const int* __restrict__ ctrl,
    const int* __restrict__ cand2_idx, const float* __restrict__ x,
    const float* __restrict__ Wdec, const float* __restrict__ benc,
    const double* __restrict__ g64, double* __restrict__ cand2_sc) {
  __shared__ double lds[4];
  int n2 = ctrl[12]; if (n2 > CAND2_CAP) n2 = CAND2_CAP;
  int t = threadIdx.x;
  for (int c = blockIdx.x; c < n2; c += gridDim.x) {
    int flat = cand2_idx[c];
    int b = flat >> 14, j = flat & (D_SAE - 1);
    double d[4];
    ln_row_fp64(x + (size_t)b * (2 * D_MODEL), lds, d);
    float4 w4 = *(const float4*)(Wdec + (size_t)j * D_MODEL + t * 4);
    double a = d[0] * (double)w4.x + d[1] * (double)w4.y + d[2] * (double)w4.z + d[3] * (double)w4.w;
    double z = blockReduceSum256(a, lds) + (double)benc[j];
    double sc = z > 0 ? z * g64[j] : 0.0;
    if (t == 0) cand2_sc[c] = sc;
  }
}

// ---------- rank band candidates (fp64, index-stable), accept fill ----------
__global__ __launch_bounds__(256) void cand2_rank_kernel(const int* __restrict__ ctrl,
    const int* __restrict__ cand2_idx, const double* __restrict__ cand2_sc,
    const double* __restrict__ g64, const int* __restrict__ kptr,
    int* row_cnt, int* row_feat, float* row_act) {
  __shared__ int lds[4];
  int n2 = ctrl[12]; if (n2 > CAND2_CAP) n2 = CAND2_CAP;
  int kB = kptr[0] * BATCH;
  int fill = kB - ctrl[11];
  int t = threadIdx.x;
  for (int c = blockIdx.x; c < n2; c += gridDim.x) {
    double sc = cand2_sc[c];
    int fc = cand2_idx[c];
    int cnt = 0;
    for (int y = t; y < n2; y += 256) {
      double sy = cand2_sc[y];
      if (sy > sc || (sy == sc && cand2_idx[y] < fc)) cnt++;
    }
    cnt = blockReduceSumInt256(cnt, lds);
    if (t == 0 && cnt < fill) {
      int b = fc >> 14, j = fc & (D_SAE - 1);
      int p = atomicAdd(&row_cnt[b], 1);
      if (p < ROW_CAP) { row_feat[b * ROW_CAP + p] = j; row_act[b * ROW_CAP + p] = (float)(sc / g64[j]); }
    }
  }
}

// ---------- sparse recon ----------
__global__ __launch_bounds__(256) void recon_kernel(const int* __restrict__ row_cnt,
    const int* __restrict__ row_feat, const float* __restrict__ row_act,
    const float* __restrict__ Wdec, const float* __restrict__ bdec, float* __restrict__ out) {
  int b = blockIdx.x, t = threadIdx.x;
  float a0 = bdec[t], a1 = bdec[t + 256], a2 = bdec[t + 512], a3 = bdec[t + 768];
  int n = row_cnt[b]; if (n > ROW_CAP) n = ROW_CAP;
  const int* rf = row_feat + (size_t)b * ROW_CAP;
  const float* ra = row_act + (size_t)b * ROW_CAP;
  for (int p = 0; p < n; p++) {
    int j = rf[p]; float a = ra[p];
    const float* wr = Wdec + (size_t)j * D_MODEL;
    a0 += a * wr[t]; a1 += a * wr[t + 256]; a2 += a * wr[t + 512]; a3 += a * wr[t + 768];
  }
  float* o = out + (size_t)b * D_MODEL;
  o[t] = a0; o[t + 256] = a1; o[t + 512] = a2; o[t + 768] = a3;
}

extern "C" void kernel_launch(void* const* d_in, const int* in_sizes, int n_in,
                              void* d_out, int out_size, void* d_ws, size_t ws_size,
                              hipStream_t stream) {
  const float* x    = (const float*)d_in[0];
  const float* Wenc = (const float*)d_in[1];
  const float* benc = (const float*)d_in[2];
  const float* Wdec = (const float*)d_in[3];
  const float* bdec = (const float*)d_in[4];
  const int*   kptr = (const int*)d_in[5];
  float* out = (float*)d_out;

  char* ws = (char*)d_ws;
  size_t off = 0;
  short*  Ahi       = (short*)(ws + off);  off += (size_t)BATCH * D_MODEL * 2;   // 8.4 MB
  short*  Alo       = (short*)(ws + off);  off += (size_t)BATCH * D_MODEL * 2;   // 8.4 MB
  int*    cand_idx  = (int*)(ws + off);    off += (size_t)CAND_CAP * 4;          // 16.8 MB
  float*  cand_sc   = (float*)(ws + off);  off += (size_t)CAND_CAP * 4;          // 16.8 MB
  int*    row_feat  = (int*)(ws + off);    off += (size_t)BATCH * ROW_CAP * 4;   // 4.2 MB
  float*  row_act   = (float*)(ws + off);  off += (size_t)BATCH * ROW_CAP * 4;   // 4.2 MB
  int*    cand2_idx = (int*)(ws + off);    off += (size_t)CAND2_CAP * 4;
  double* cand2_sc  = (double*)(ws + off); off += (size_t)CAND2_CAP * 8;
  double* g64       = (double*)(ws + off); off += (size_t)D_SAE * 8;
  float*  g32       = (float*)(ws + off);  off += (size_t)D_SAE * 4;
  char*   zbase     = ws + off;
  int* ghist   = (int*)(zbase);
  int* h1      = (int*)(zbase + 8192);
  int* h2      = (int*)(zbase + 16384);
  int* h3      = (int*)(zbase + 24576);
  int* ctrl    = (int*)(zbase + 28672);
  int* row_cnt = (int*)(zbase + 28928);
  size_t zbytes = 28928 + (size_t)BATCH * 4;
  if (off + zbytes > ws_size) return;  // needs ~60 MB (round-2-proven size)

  hipMemsetAsync(zbase, 0, zbytes, stream);

  ln_kernel<<<BATCH, 256, 0, stream>>>(x, Ahi, Alo);
  norm_kernel<<<D_SAE, 256, 0, stream>>>(Wdec, g64, g32);
  mfma_gemm<0><<<4096, 256, 0, stream>>>(Wenc, Ahi, Alo, benc, g32, ghist, ctrl, nullptr, nullptr);
  find_coarse_kernel<<<1, 1, 0, stream>>>(ghist, ctrl, kptr);
  mfma_gemm<1><<<4096, 256, 0, stream>>>(Wenc, Ahi, Alo, benc, g32, nullptr, ctrl, cand_idx, cand_sc);
  chist_kernel<<<1024, 256, 0, stream>>>(cand_sc, ctrl, h1, 0);
  cfind_kernel<<<1, 1, 0, stream>>>(h1, ctrl, kptr, 0);
  chist_kernel<<<1024, 256, 0, stream>>>(cand_sc, ctrl, h2, 1);
  cfind_kernel<<<1, 1, 0, stream>>>(h2, ctrl, kptr, 1);
  chist_kernel<<<1024, 256, 0, stream>>>(cand_sc, ctrl, h3, 2);
  cfind_kernel<<<1, 1, 0, stream>>>(h3, ctrl, kptr, 2);
  band_kernel<<<1024, 256, 0, stream>>>(cand_idx, cand_sc, g32, ctrl, row_cnt, row_feat, row_act, cand2_idx);
  cand2_score_kernel<<<4096, 256, 0, stream>>>(ctrl, cand2_idx, x, Wdec, benc, g64, cand2_sc);
  cand2_rank_kernel<<<2048, 256, 0, stream>>>(ctrl, cand2_idx, cand2_sc, g64, kptr, row_cnt, row_feat, row_act);
  recon_kernel<<<BATCH, 256, 0, stream>>>(row_cnt, row_feat, row_act, Wdec, bdec, out);
}

// Round 6
// 1253.206 us; speedup vs baseline: 5.4705x; 1.3677x over previous
//
#include <hip/hip_runtime.h>
#include <math.h>

#define D_MODEL 1024
#define D_SAE   16384
#define BATCH   4096
#define NTOT    (1ull * BATCH * D_SAE)
#define LN_EPS  1e-8
#define EPS_M   1e-3f        // |split-bf16 score - fp64 score| safe band half-width
#define ROW_CAP 256
#define CAND_CAP  (4 * 1024 * 1024)
#define CAND2_CAP 65536

using bf16x8 = __attribute__((ext_vector_type(8))) short;
using f32x4  = __attribute__((ext_vector_type(4))) float;

__device__ inline unsigned short f2bf(float f) {   // RNE fp32->bf16
  unsigned u = __float_as_uint(f);
  return (unsigned short)((u + 0x7fffu + ((u >> 16) & 1u)) >> 16);
}
__device__ inline float bf2f(unsigned short h) {
  return __uint_as_float((unsigned)h << 16);
}

// ---------- block (256-thread) reductions ----------
__device__ inline double blockReduceSum256(double v, double* lds) {
#pragma unroll
  for (int off = 32; off > 0; off >>= 1) v += __shfl_down(v, off, 64);
  int lane = threadIdx.x & 63, wid = threadIdx.x >> 6;
  __syncthreads();
  if (lane == 0) lds[wid] = v;
  __syncthreads();
  return lds[0] + lds[1] + lds[2] + lds[3];
}
__device__ inline int blockReduceSumInt256(int v, int* lds) {
#pragma unroll
  for (int off = 32; off > 0; off >>= 1) v += __shfl_down(v, off, 64);
  int lane = threadIdx.x & 63, wid = threadIdx.x >> 6;
  __syncthreads();
  if (lane == 0) lds[wid] = v;
  __syncthreads();
  return lds[0] + lds[1] + lds[2] + lds[3];
}

__device__ inline int wave_append(bool pred, int* counter) {
  unsigned long long m = __ballot(pred);
  int lane = threadIdx.x & 63;
  int pos = -1;
  if (m) {
    int ldr = __ffsll((long long)m) - 1;
    int base = 0;
    if (lane == ldr) base = atomicAdd(counter, __popcll(m));
    base = __shfl(base, ldr, 64);
    if (pred) pos = base + __popcll(m & ((1ull << lane) - 1ull));
  }
  return pos;
}

// ---------- per-thread fp64 LN chain: thread t owns elements t*4..t*4+3 ----------
__device__ inline void ln_row_fp64(const float* __restrict__ row, double* lds, double d[4]) {
  int t = threadIdx.x;
  float4 s4 = *(const float4*)(row + t * 4);
  float4 t4 = *(const float4*)(row + D_MODEL + t * 4);
  double s[4] = {s4.x, s4.y, s4.z, s4.w};
  double tt[4] = {t4.x, t4.y, t4.z, t4.w};
  double ms = blockReduceSum256(s[0] + s[1] + s[2] + s[3], lds) / D_MODEL;
  double mt = blockReduceSum256(tt[0] + tt[1] + tt[2] + tt[3], lds) / D_MODEL;
  double vs = 0, vt = 0;
#pragma unroll
  for (int i = 0; i < 4; i++) { double a = s[i] - ms; vs += a * a; a = tt[i] - mt; vt += a * a; }
  vs = blockReduceSum256(vs, lds) / D_MODEL;
  vt = blockReduceSum256(vt, lds) / D_MODEL;
  double rs = sqrt(vs + LN_EPS), rt = sqrt(vt + LN_EPS);
  double u[4];
#pragma unroll
  for (int i = 0; i < 4; i++) u[i] = (tt[i] - mt) / rt - (s[i] - ms) / rs;
  double mu = blockReduceSum256(u[0] + u[1] + u[2] + u[3], lds) / D_MODEL;
  double vu = 0;
#pragma unroll
  for (int i = 0; i < 4; i++) { double a = u[i] - mu; vu += a * a; }
  vu = blockReduceSum256(vu, lds) / D_MODEL;
  double ru = sqrt(vu + LN_EPS);
#pragma unroll
  for (int i = 0; i < 4; i++) d[i] = (u[i] - mu) / ru;
}

// ---------- LN -> split-bf16 A in GEMM-tiled layout [mt][ks][kc][ml][e] ----------
__global__ __launch_bounds__(256) void ln_kernel(const float* __restrict__ x,
                                                 short* __restrict__ Ahi, short* __restrict__ Alo) {
  __shared__ double lds[4];
  int b = blockIdx.x, t = threadIdx.x;
  double d[4];
  ln_row_fp64(x + (size_t)b * (2 * D_MODEL), lds, d);
  int mt = b >> 7, ml = b & 127;
  int ks = t >> 3, kc = (t >> 1) & 3, e0 = (t & 1) * 4;
  size_t base = ((((size_t)mt * 32 + ks) * 4 + kc) * 128 + ml) * 8 + e0;
  short h[4], l[4];
#pragma unroll
  for (int i = 0; i < 4; i++) {
    float f = (float)d[i];
    unsigned short hh = f2bf(f);
    h[i] = (short)hh;
    l[i] = (short)f2bf(f - bf2f(hh));
  }
  *(short4*)&Ahi[base] = make_short4(h[0], h[1], h[2], h[3]);
  *(short4*)&Alo[base] = make_short4(l[0], l[1], l[2], l[3]);
}

// ---------- dec_norms in fp64 ----------
__global__ __launch_bounds__(256) void norm_kernel(const float* __restrict__ Wdec,
                                                   double* __restrict__ g64, float* __restrict__ g32) {
  __shared__ double lds[4];
  int j = blockIdx.x, t = threadIdx.x;
  float4 w = *(const float4*)(Wdec + (size_t)j * D_MODEL + t * 4);
  double a = (double)w.x * w.x + (double)w.y * w.y + (double)w.z * w.z + (double)w.w * w.w;
  double sum = blockReduceSum256(a, lds);
  if (t == 0) { double g = sqrt(sum); g64[j] = g; g32[j] = (float)g; }
}

// ---------- pre-split W_enc fp32 -> tiled bf16 hi/lo [nt][ks][kc][c][e] ----------
__global__ __launch_bounds__(256) void wsplit_kernel(const float* __restrict__ Wenc,
                                                     short* __restrict__ Whi, short* __restrict__ Wlo) {
  __shared__ short sh[4096];
  __shared__ short sl[4096];
  int blk = blockIdx.x;            // 4096 = 128 nt * 32 ks
  int nt = blk >> 5, ks = blk & 31;
  int t = threadIdx.x;
  int r = t >> 3;                  // k within step, 0..31
  int cg = t & 7;                  // column sub-lane
  int kc = r >> 3, e = r & 7;
  const float* src = Wenc + (size_t)(ks * 32 + r) * D_SAE + nt * 128 + cg;
#pragma unroll
  for (int j = 0; j < 16; ++j) {
    float f = src[j * 8];
    unsigned short hh = f2bf(f);
    short ll = (short)f2bf(f - bf2f(hh));
    int c = j * 8 + cg;
    sh[kc * 1024 + c * 8 + e] = (short)hh;
    sl[kc * 1024 + c * 8 + e] = ll;
  }
  __syncthreads();
  size_t obase = ((size_t)nt * 32 + ks) * 4096;
  *(float4*)&Whi[obase + t * 16]     = *(const float4*)&sh[t * 16];
  *(float4*)&Whi[obase + t * 16 + 8] = *(const float4*)&sh[t * 16 + 8];
  *(float4*)&Wlo[obase + t * 16]     = *(const float4*)&sl[t * 16];
  *(float4*)&Wlo[obase + t * 16 + 8] = *(const float4*)&sl[t * 16 + 8];
}

// ---------- split-bf16 MFMA score GEMM ----------
// MODE 0 = subsampled histogram (grid 256: 2 mt x 128 nt), MODE 1 = extract (grid 4096).
// PRESPLIT 1: B from pre-split Whi/Wlo tiled; PRESPLIT 0: on-the-fly fp32->hi/lo.
template <int MODE, int PRESPLIT>
__global__ __launch_bounds__(256) void mfma_gemm(
    const float* __restrict__ Wenc, const short* __restrict__ Whi, const short* __restrict__ Wlo,
    const short* __restrict__ Ahi, const short* __restrict__ Alo,
    const float* __restrict__ benc, const float* __restrict__ g32,
    int* __restrict__ ghist, int* __restrict__ ctrl,
    int* __restrict__ cand_idx, float* __restrict__ cand_sc) {
  __shared__ short sA[8192];   // Ahi tile [4][128][8] | Alo tile
  __shared__ short sB[8192];   // Bhi tile [4][128][8] | Blo tile
  __shared__ int h[(MODE == 0) ? 2048 : 2];

  const int tid = threadIdx.x;
  const int lane = tid & 63;
  const int w = tid >> 6;
  const int wm = (w >> 1) * 64, wn = (w & 1) * 64;

  int lin = blockIdx.x;
  int mt, nt;
  if (MODE == 0) {               // subsample: rows 0..255 (mt tiles 0,1)
    mt = lin >> 7; nt = lin & 127;
  } else {                       // L2-locality: XCD owns 16 nt panels; 32 blocks share a panel
    int xcd = lin & 7, j = lin >> 3;
    mt = j & 31;
    nt = (xcd << 4) | (j >> 5);
  }
  const int row0 = mt * 128, col0 = nt * 128;

  if (MODE == 0) { for (int i = tid; i < 2048; i += 256) h[i] = 0; }
  else if (tid == 0) h[0] = 0;

  const int nl = tid & 127;
  const int half = tid >> 7;  // 0,1
  const float* wbase = Wenc + (size_t)col0 + nl;
  const size_t atile = (size_t)mt * 131072;
  const size_t btile = (size_t)nt * 131072;

  f32x4 acc[4][4] = {};
  const int kcl = lane >> 4, l15 = lane & 15;

  // ---- prologue: load tile 0 into registers ----
  float4 a0, a1, a2, a3;
  float4 b0, b1, b2, b3;
  float bfv[16];
  {
    const float4* ah4 = (const float4*)(Ahi + atile);
    const float4* al4 = (const float4*)(Alo + atile);
    a0 = ah4[tid]; a1 = ah4[tid + 256];
    a2 = al4[tid]; a3 = al4[tid + 256];
    if (PRESPLIT) {
      const float4* bh4 = (const float4*)(Whi + btile);
      const float4* bl4 = (const float4*)(Wlo + btile);
      b0 = bh4[tid]; b1 = bh4[tid + 256];
      b2 = bl4[tid]; b3 = bl4[tid + 256];
    } else {
#pragma unroll
      for (int p = 0; p < 4; ++p)
#pragma unroll
        for (int i = 0; i < 4; ++i)
          bfv[p * 4 + i] = wbase[(size_t)(p * 8 + half * 4 + i) * D_SAE];
    }
  }

  for (int ks = 0; ks < 32; ++ks) {
    short hb[16], lb[16];
    if (!PRESPLIT) {
#pragma unroll
      for (int q = 0; q < 16; ++q) {
        unsigned short hh = f2bf(bfv[q]);
        hb[q] = (short)hh;
        lb[q] = (short)f2bf(bfv[q] - bf2f(hh));
      }
    }
    __syncthreads();   // previous tile fully consumed
    *(float4*)&sA[(size_t)tid * 8] = a0;
    *(float4*)&sA[(size_t)(tid + 256) * 8] = a1;
    *(float4*)&sA[(size_t)(512 + tid) * 8] = a2;
    *(float4*)&sA[(size_t)(512 + tid + 256) * 8] = a3;
    if (PRESPLIT) {
      *(float4*)&sB[(size_t)tid * 8] = b0;
      *(float4*)&sB[(size_t)(tid + 256) * 8] = b1;
      *(float4*)&sB[(size_t)(512 + tid) * 8] = b2;
      *(float4*)&sB[(size_t)(512 + tid + 256) * 8] = b3;
    } else {
#pragma unroll
      for (int p = 0; p < 4; ++p) {
        int boff = p * 1024 + nl * 8 + half * 4;
        *(short4*)&sB[boff] = make_short4(hb[p * 4], hb[p * 4 + 1], hb[p * 4 + 2], hb[p * 4 + 3]);
        *(short4*)&sB[4096 + boff] = make_short4(lb[p * 4], lb[p * 4 + 1], lb[p * 4 + 2], lb[p * 4 + 3]);
      }
    }
    __syncthreads();   // tile visible

    // ---- prefetch tile ks+1 into registers; latency hides under MFMA below ----
    if (ks < 31) {
      const float4* ah4 = (const float4*)(Ahi + atile + (ks + 1) * 4096);
      const float4* al4 = (const float4*)(Alo + atile + (ks + 1) * 4096);
      a0 = ah4[tid]; a1 = ah4[tid + 256];
      a2 = al4[tid]; a3 = al4[tid + 256];
      if (PRESPLIT) {
        const float4* bh4 = (const float4*)(Whi + btile + (ks + 1) * 4096);
        const float4* bl4 = (const float4*)(Wlo + btile + (ks + 1) * 4096);
        b0 = bh4[tid]; b1 = bh4[tid + 256];
        b2 = bl4[tid]; b3 = bl4[tid + 256];
      } else {
        const int k0n = (ks + 1) * 32;
#pragma unroll
        for (int p = 0; p < 4; ++p)
#pragma unroll
          for (int i = 0; i < 4; ++i)
            bfv[p * 4 + i] = wbase[(size_t)(k0n + p * 8 + half * 4 + i) * D_SAE];
      }
    }

    // fragments + MFMA (A row=lane&15, k=(lane>>4)*8+e)
    bf16x8 ahf[4], alf[4];
#pragma unroll
    for (int fm = 0; fm < 4; ++fm) {
      int off = (kcl * 128 + wm + fm * 16 + l15) * 8;
      ahf[fm] = *(const bf16x8*)&sA[off];
      alf[fm] = *(const bf16x8*)&sA[4096 + off];
    }
#pragma unroll
    for (int fn = 0; fn < 4; ++fn) {
      int boff = (kcl * 128 + wn + fn * 16 + l15) * 8;
      bf16x8 bh = *(const bf16x8*)&sB[boff];
      bf16x8 bl = *(const bf16x8*)&sB[4096 + boff];
#pragma unroll
      for (int fm = 0; fm < 4; ++fm) {
        acc[fm][fn] = __builtin_amdgcn_mfma_f32_16x16x32_bf16(ahf[fm], bh, acc[fm][fn], 0, 0, 0);
        acc[fm][fn] = __builtin_amdgcn_mfma_f32_16x16x32_bf16(alf[fm], bh, acc[fm][fn], 0, 0, 0);
        acc[fm][fn] = __builtin_amdgcn_mfma_f32_16x16x32_bf16(ahf[fm], bl, acc[fm][fn], 0, 0, 0);
      }
    }
  }

  // epilogue: C col=lane&15, row=(lane>>4)*4+r (m89-verified)
  const int l4r = lane >> 4;
  if (MODE == 0) {
#pragma unroll
    for (int fn = 0; fn < 4; ++fn) {
      int col = col0 + wn + fn * 16 + l15;
      float g = g32[col], be = benc[col];
#pragma unroll
      for (int fm = 0; fm < 4; ++fm) {
#pragma unroll
        for (int r = 0; r < 4; ++r) {
          float z = acc[fm][fn][r] + be;
          float s = z > 0.f ? z * g : 0.f;
          unsigned bits = __float_as_uint(s);
          if (bits) atomicAdd(&h[bits >> 21], 1);
        }
      }
    }
    __syncthreads();
    for (int i = tid; i < 2048; i += 256)
      if (h[i]) atomicAdd(&ghist[i], h[i]);
  } else {
    // block-aggregated append: count -> one global atomic -> write
    unsigned thrBits = (unsigned)ctrl[1];
    int cnt = 0;
#pragma unroll
    for (int fn = 0; fn < 4; ++fn) {
      int col = col0 + wn + fn * 16 + l15;
      float g = g32[col], be = benc[col];
#pragma unroll
      for (int fm = 0; fm < 4; ++fm) {
#pragma unroll
        for (int r = 0; r < 4; ++r) {
          float z = acc[fm][fn][r] + be;
          float s = z > 0.f ? z * g : 0.f;
          cnt += (__float_as_uint(s) >= thrBits) ? 1 : 0;
        }
      }
    }
    int my = 0;
    if (cnt) my = atomicAdd(&h[0], cnt);
    __syncthreads();
    if (tid == 0) h[1] = atomicAdd(&ctrl[2], h[0]);
    __syncthreads();
    int pos = h[1] + my;
#pragma unroll
    for (int fn = 0; fn < 4; ++fn) {
      int col = col0 + wn + fn * 16 + l15;
      float g = g32[col], be = benc[col];
#pragma unroll
      for (int fm = 0; fm < 4; ++fm) {
        int rowb = row0 + wm + fm * 16 + l4r * 4;
#pragma unroll
        for (int r = 0; r < 4; ++r) {
          float z = acc[fm][fn][r] + be;
          float s = z > 0.f ? z * g : 0.f;
          if (__float_as_uint(s) >= thrBits) {
            if (pos < CAND_CAP) { cand_idx[pos] = (rowb + r) * D_SAE + col; cand_sc[pos] = s; }
            pos++;
          }
        }
      }
    }
  }
}

// ---------- coarse threshold from 1/16-subsampled hist, with margins ----------
__global__ void find_coarse_kernel(const int* __restrict__ gh, int* ctrl,
                                   const int* __restrict__ kptr) {
  if (threadIdx.x || blockIdx.x) return;
  long long kB = (long long)kptr[0] * BATCH;
  long long need_samp = (kB + 500000 + 15) / 16;        // full-scale est >= kB+500K
  if (need_samp < 45000) need_samp = 45000;             // >= ~720K full
  long long cum = 0;
  int b = 2047;
  for (; b > 0; b--) {
    long long c = gh[b];
    if (cum + c >= need_samp) break;
    cum += c;
  }
  // dense-bin guard: if extraction estimate blows past cap, shrink by one bin
  long long est_incl = 16LL * (cum + gh[b]);
  if (est_incl > 3500000LL && 16LL * cum >= kB + 120000LL) b = b + 1;
  ctrl[1] = (int)(((unsigned)b) << 21);
}

// ---------- radix histograms over candidate scores ----------
__global__ __launch_bounds__(256) void chist_kernel(const float* __restrict__ cand_sc,
                                                    const int* __restrict__ ctrl,
                                                    int* __restrict__ ghist, int pass) {
  __shared__ int h[2048];
  int nb = (pass == 2) ? 1024 : 2048;
  for (int i = threadIdx.x; i < nb; i += 256) h[i] = 0;
  __syncthreads();
  int n = ctrl[2]; if (n > CAND_CAP) n = CAND_CAP;
  unsigned sel1 = 0, sel22 = 0;
  if (pass == 1) sel1 = (unsigned)ctrl[3];
  if (pass == 2) sel22 = ((unsigned)ctrl[3] << 11) | (unsigned)ctrl[5];
  for (int i = blockIdx.x * 256 + threadIdx.x; i < n; i += gridDim.x * 256) {
    unsigned bits = __float_as_uint(cand_sc[i]);
    if (pass == 0) atomicAdd(&h[bits >> 21], 1);
    else if (pass == 1) { if ((bits >> 21) == sel1) atomicAdd(&h[(bits >> 10) & 0x7FFu], 1); }
    else { if ((bits >> 10) == sel22) atomicAdd(&h[bits & 0x3FFu], 1); }
  }
  __syncthreads();
  for (int i = threadIdx.x; i < nb; i += 256)
    if (h[i]) atomicAdd(&ghist[i], h[i]);
}

__global__ void cfind_kernel(const int* __restrict__ hist, int* ctrl,
                             const int* __restrict__ kptr, int pass) {
  if (threadIdx.x || blockIdx.x) return;
  int kB = kptr[0] * BATCH;
  int need, nbins;
  if (pass == 0)      { need = kB;                       nbins = 2048; }
  else if (pass == 1) { need = kB - ctrl[4];             nbins = 2048; }
  else                { need = kB - ctrl[4] - ctrl[6];   nbins = 1024; }
  int cum = 0, b = nbins - 1;
  for (; b > 0; b--) {
    int c = hist[b];
    if (cum + c >= need) break;
    cum += c;
  }
  if (pass == 0)      { ctrl[3] = b; ctrl[4] = cum; }
  else if (pass == 1) { ctrl[5] = b; ctrl[6] = cum; }
  else {
    unsigned vbits = ((unsigned)ctrl[3] << 21) | ((unsigned)ctrl[5] << 10) | (unsigned)b;
    float V = __uint_as_float(vbits);
    float* cf = (float*)ctrl;
    cf[8] = V; cf[9] = V + EPS_M; cf[10] = V - EPS_M;
  }
}

// ---------- band partition ----------
__global__ __launch_bounds__(256) void band_kernel(const int* __restrict__ cand_idx,
    const float* __restrict__ cand_sc, const float* __restrict__ g32,
    int* ctrl, int* row_cnt, int* row_feat, float* row_act, int* cand2_idx) {
  const float* cf = (const float*)ctrl;
  float hi = cf[9], lo = cf[10];
  int n = ctrl[2]; if (n > CAND_CAP) n = CAND_CAP;
  int lane = threadIdx.x & 63;
  int defc = 0;
  for (int i = blockIdx.x * 256 + threadIdx.x; i < n; i += gridDim.x * 256) {
    float s = cand_sc[i];
    int flat = cand_idx[i];
    if (s > hi) {
      int b = flat >> 14, j = flat & (D_SAE - 1);
      int p = atomicAdd(&row_cnt[b], 1);
      if (p < ROW_CAP) { row_feat[b * ROW_CAP + p] = j; row_act[b * ROW_CAP + p] = s / g32[j]; }
      defc++;
    }
    bool isc = (s <= hi) && (s >= lo);
    int pos = wave_append(isc, &ctrl[12]);
    if (isc && pos >= 0 && pos < CAND2_CAP) cand2_idx[pos] = flat;
  }
#pragma unroll
  for (int off = 32; off > 0; off >>= 1) defc += __shfl_down(defc, off, 64);
  if (lane == 0 && defc) atomicAdd(&ctrl[11], defc);
}

// ---------- fp64 rescore of band candidates ----------
__global__ __launch_bounds__(256) void cand2_score_kernel(const int* __restrict__ ctrl,
    const int* __restrict__ cand2_idx, const float* __restrict__ x,
    const float* __restrict__ Wdec, const float* __restrict__ benc,
    const double* __restrict__ g64, double* __restrict__ cand2_sc) {
  __shared__ double lds[4];
  int n2 = ctrl[12]; if (n2 > CAND2_CAP) n2 = CAND2_CAP;
  int t = threadIdx.x;
  for (int c = blockIdx.x; c < n2; c += gridDim.x) {
    int flat = cand2_idx[c];
    int b = flat >> 14, j = flat & (D_SAE - 1);
    double d[4];
    ln_row_fp64(x + (size_t)b * (2 * D_MODEL), lds, d);
    float4 w4 = *(const float4*)(Wdec + (size_t)j * D_MODEL + t * 4);
    double a = d[0] * (double)w4.x + d[1] * (double)w4.y + d[2] * (double)w4.z + d[3] * (double)w4.w;
    double z = blockReduceSum256(a, lds) + (double)benc[j];
    double sc = z > 0 ? z * g64[j] : 0.0;
    if (t == 0) cand2_sc[c] = sc;
  }
}

// ---------- rank band candidates (fp64, index-stable), accept fill ----------
__global__ __launch_bounds__(256) void cand2_rank_kernel(const int* __restrict__ ctrl,
    const int* __restrict__ cand2_idx, const double* __restrict__ cand2_sc,
    const double* __restrict__ g64, const int* __restrict__ kptr,
    int* row_cnt, int* row_feat, float* row_act) {
  __shared__ int lds[4];
  int n2 = ctrl[12]; if (n2 > CAND2_CAP) n2 = CAND2_CAP;
  int kB = kptr[0] * BATCH;
  int fill = kB - ctrl[11];
  int t = threadIdx.x;
  for (int c = blockIdx.x; c < n2; c += gridDim.x) {
    double sc = cand2_sc[c];
    int fc = cand2_idx[c];
    int cnt = 0;
    for (int y = t; y < n2; y += 256) {
      double sy = cand2_sc[y];
      if (sy > sc || (sy == sc && cand2_idx[y] < fc)) cnt++;
    }
    cnt = blockReduceSumInt256(cnt, lds);
    if (t == 0 && cnt < fill) {
      int b = fc >> 14, j = fc & (D_SAE - 1);
      int p = atomicAdd(&row_cnt[b], 1);
      if (p < ROW_CAP) { row_feat[b * ROW_CAP + p] = j; row_act[b * ROW_CAP + p] = (float)(sc / g64[j]); }
    }
  }
}

// ---------- sparse recon (vectorized float4) ----------
__global__ __launch_bounds__(256) void recon_kernel(const int* __restrict__ row_cnt,
    const int* __restrict__ row_feat, const float* __restrict__ row_act,
    const float* __restrict__ Wdec, const float* __restrict__ bdec, float* __restrict__ out) {
  int b = blockIdx.x, t = threadIdx.x;
  float4 a = *(const float4*)&bdec[t * 4];
  int n = row_cnt[b]; if (n > ROW_CAP) n = ROW_CAP;
  const int* rf = row_feat + (size_t)b * ROW_CAP;
  const float* ra = row_act + (size_t)b * ROW_CAP;
  for (int p = 0; p < n; p++) {
    int j = rf[p]; float av = ra[p];
    float4 wv = *(const float4*)(Wdec + (size_t)j * D_MODEL + t * 4);
    a.x += av * wv.x; a.y += av * wv.y; a.z += av * wv.z; a.w += av * wv.w;
  }
  *(float4*)(out + (size_t)b * D_MODEL + t * 4) = a;
}

extern "C" void kernel_launch(void* const* d_in, const int* in_sizes, int n_in,
                              void* d_out, int out_size, void* d_ws, size_t ws_size,
                              hipStream_t stream) {
  const float* x    = (const float*)d_in[0];
  const float* Wenc = (const float*)d_in[1];
  const float* benc = (const float*)d_in[2];
  const float* Wdec = (const float*)d_in[3];
  const float* bdec = (const float*)d_in[4];
  const int*   kptr = (const int*)d_in[5];
  float* out = (float*)d_out;

  char* ws = (char*)d_ws;
  size_t off = 0;
  short*  Ahi       = (short*)(ws + off);  off += (size_t)BATCH * D_MODEL * 2;   // 8.4 MB
  short*  Alo       = (short*)(ws + off);  off += (size_t)BATCH * D_MODEL * 2;   // 8.4 MB
  int*    cand_idx  = (int*)(ws + off);    off += (size_t)CAND_CAP * 4;          // 16.8 MB
  float*  cand_sc   = (float*)(ws + off);  off += (size_t)CAND_CAP * 4;          // 16.8 MB
  int*    row_feat  = (int*)(ws + off);    off += (size_t)BATCH * ROW_CAP * 4;   // 4.2 MB
  float*  row_act   = (float*)(ws + off);  off += (size_t)BATCH * ROW_CAP * 4;   // 4.2 MB
  int*    cand2_idx = (int*)(ws + off);    off += (size_t)CAND2_CAP * 4;
  double* cand2_sc  = (double*)(ws + off); off += (size_t)CAND2_CAP * 8;
  double* g64       = (double*)(ws + off); off += (size_t)D_SAE * 8;
  float*  g32       = (float*)(ws + off);  off += (size_t)D_SAE * 4;
  char*   zbase     = ws + off;
  int* ghist   = (int*)(zbase);
  int* h1      = (int*)(zbase + 8192);
  int* h2      = (int*)(zbase + 16384);
  int* h3      = (int*)(zbase + 24576);
  int* ctrl    = (int*)(zbase + 28672);
  int* row_cnt = (int*)(zbase + 28928);
  size_t zbytes = 28928 + (size_t)BATCH * 4;
  size_t small_need = off + zbytes;
  if (small_need > ws_size) return;  // ~60 MB floor (round-2-proven)

  // optional pre-split W buffers (+67 MB) — used only if ws is big enough
  size_t big_off = (small_need + 255) & ~(size_t)255;
  short* Whi = (short*)(ws + big_off);
  short* Wlo = Whi + (size_t)D_MODEL * D_SAE;
  size_t big_need = big_off + (size_t)D_MODEL * D_SAE * 4;
  const bool big = (big_need <= ws_size);

  hipMemsetAsync(zbase, 0, zbytes, stream);

  ln_kernel<<<BATCH, 256, 0, stream>>>(x, Ahi, Alo);
  norm_kernel<<<D_SAE, 256, 0, stream>>>(Wdec, g64, g32);
  if (big) {
    wsplit_kernel<<<4096, 256, 0, stream>>>(Wenc, Whi, Wlo);
    mfma_gemm<0, 1><<<256, 256, 0, stream>>>(Wenc, Whi, Wlo, Ahi, Alo, benc, g32, ghist, ctrl, nullptr, nullptr);
    find_coarse_kernel<<<1, 1, 0, stream>>>(ghist, ctrl, kptr);
    mfma_gemm<1, 1><<<4096, 256, 0, stream>>>(Wenc, Whi, Wlo, Ahi, Alo, benc, g32, nullptr, ctrl, cand_idx, cand_sc);
  } else {
    mfma_gemm<0, 0><<<256, 256, 0, stream>>>(Wenc, nullptr, nullptr, Ahi, Alo, benc, g32, ghist, ctrl, nullptr, nullptr);
    find_coarse_kernel<<<1, 1, 0, stream>>>(ghist, ctrl, kptr);
    mfma_gemm<1, 0><<<4096, 256, 0, stream>>>(Wenc, nullptr, nullptr, Ahi, Alo, benc, g32, nullptr, ctrl, cand_idx, cand_sc);
  }
  chist_kernel<<<1024, 256, 0, stream>>>(cand_sc, ctrl, h1, 0);
  cfind_kernel<<<1, 1, 0, stream>>>(h1, ctrl, kptr, 0);
  chist_kernel<<<1024, 256, 0, stream>>>(cand_sc, ctrl, h2, 1);
  cfind_kernel<<<1, 1, 0, stream>>>(h2, ctrl, kptr, 1);
  chist_kernel<<<1024, 256, 0, stream>>>(cand_sc, ctrl, h3, 2);
  cfind_kernel<<<1, 1, 0, stream>>>(h3, ctrl, kptr, 2);
  band_kernel<<<1024, 256, 0, stream>>>(cand_idx, cand_sc, g32, ctrl, row_cnt, row_feat, row_act, cand2_idx);
  cand2_score_kernel<<<4096, 256, 0, stream>>>(ctrl, cand2_idx, x, Wdec, benc, g64, cand2_sc);
  cand2_rank_kernel<<<2048, 256, 0, stream>>>(ctrl, cand2_idx, cand2_sc, g64, kptr, row_cnt, row_feat, row_act);
  recon_kernel<<<BATCH, 256, 0, stream>>>(row_cnt, row_feat, row_act, Wdec, bdec, out);
}

// Round 8
// 1237.820 us; speedup vs baseline: 5.5385x; 1.0124x over previous
//
#include <hip/hip_runtime.h>
#include <math.h>

#define D_MODEL 1024
#define D_SAE   16384
#define BATCH   4096
#define NTOT    (1ull * BATCH * D_SAE)
#define LN_EPS  1e-8
#define EPS_M   1e-3f        // |split-bf16 score - fp64 score| safe band half-width
#define ROW_CAP 256
#define CAND_CAP  (4 * 1024 * 1024)
#define CAND2_CAP 65536

using bf16x8 = __attribute__((ext_vector_type(8))) short;
using f32x4  = __attribute__((ext_vector_type(4))) float;

__device__ inline unsigned short f2bf(float f) {   // RNE fp32->bf16
  unsigned u = __float_as_uint(f);
  return (unsigned short)((u + 0x7fffu + ((u >> 16) & 1u)) >> 16);
}
__device__ inline float bf2f(unsigned short h) {
  return __uint_as_float((unsigned)h << 16);
}

// ---------- block (256-thread) reductions ----------
__device__ inline double blockReduceSum256(double v, double* lds) {
#pragma unroll
  for (int off = 32; off > 0; off >>= 1) v += __shfl_down(v, off, 64);
  int lane = threadIdx.x & 63, wid = threadIdx.x >> 6;
  __syncthreads();
  if (lane == 0) lds[wid] = v;
  __syncthreads();
  return lds[0] + lds[1] + lds[2] + lds[3];
}
__device__ inline int blockReduceSumInt256(int v, int* lds) {
#pragma unroll
  for (int off = 32; off > 0; off >>= 1) v += __shfl_down(v, off, 64);
  int lane = threadIdx.x & 63, wid = threadIdx.x >> 6;
  __syncthreads();
  if (lane == 0) lds[wid] = v;
  __syncthreads();
  return lds[0] + lds[1] + lds[2] + lds[3];
}

__device__ inline int wave_append(bool pred, int* counter) {
  unsigned long long m = __ballot(pred);
  int lane = threadIdx.x & 63;
  int pos = -1;
  if (m) {
    int ldr = __ffsll((long long)m) - 1;
    int base = 0;
    if (lane == ldr) base = atomicAdd(counter, __popcll(m));
    base = __shfl(base, ldr, 64);
    if (pred) pos = base + __popcll(m & ((1ull << lane) - 1ull));
  }
  return pos;
}

// ---------- per-thread fp64 LN chain: thread t owns elements t*4..t*4+3 ----------
__device__ inline void ln_row_fp64(const float* __restrict__ row, double* lds, double d[4]) {
  int t = threadIdx.x;
  float4 s4 = *(const float4*)(row + t * 4);
  float4 t4 = *(const float4*)(row + D_MODEL + t * 4);
  double s[4] = {s4.x, s4.y, s4.z, s4.w};
  double tt[4] = {t4.x, t4.y, t4.z, t4.w};
  double ms = blockReduceSum256(s[0] + s[1] + s[2] + s[3], lds) / D_MODEL;
  double mt = blockReduceSum256(tt[0] + tt[1] + tt[2] + tt[3], lds) / D_MODEL;
  double vs = 0, vt = 0;
#pragma unroll
  for (int i = 0; i < 4; i++) { double a = s[i] - ms; vs += a * a; a = tt[i] - mt; vt += a * a; }
  vs = blockReduceSum256(vs, lds) / D_MODEL;
  vt = blockReduceSum256(vt, lds) / D_MODEL;
  double rs = sqrt(vs + LN_EPS), rt = sqrt(vt + LN_EPS);
  double u[4];
#pragma unroll
  for (int i = 0; i < 4; i++) u[i] = (tt[i] - mt) / rt - (s[i] - ms) / rs;
  double mu = blockReduceSum256(u[0] + u[1] + u[2] + u[3], lds) / D_MODEL;
  double vu = 0;
#pragma unroll
  for (int i = 0; i < 4; i++) { double a = u[i] - mu; vu += a * a; }
  vu = blockReduceSum256(vu, lds) / D_MODEL;
  double ru = sqrt(vu + LN_EPS);
#pragma unroll
  for (int i = 0; i < 4; i++) d[i] = (u[i] - mu) / ru;
}

// ---------- LN -> split-bf16 A in GEMM-tiled layout [mt][ks][kc][ml][e] ----------
__global__ __launch_bounds__(256) void ln_kernel(const float* __restrict__ x,
                                                 short* __restrict__ Ahi, short* __restrict__ Alo) {
  __shared__ double lds[4];
  int b = blockIdx.x, t = threadIdx.x;
  double d[4];
  ln_row_fp64(x + (size_t)b * (2 * D_MODEL), lds, d);
  int mt = b >> 7, ml = b & 127;
  int ks = t >> 3, kc = (t >> 1) & 3, e0 = (t & 1) * 4;
  size_t base = ((((size_t)mt * 32 + ks) * 4 + kc) * 128 + ml) * 8 + e0;
  short h[4], l[4];
#pragma unroll
  for (int i = 0; i < 4; i++) {
    float f = (float)d[i];
    unsigned short hh = f2bf(f);
    h[i] = (short)hh;
    l[i] = (short)f2bf(f - bf2f(hh));
  }
  *(short4*)&Ahi[base] = make_short4(h[0], h[1], h[2], h[3]);
  *(short4*)&Alo[base] = make_short4(l[0], l[1], l[2], l[3]);
}

// ---------- dec_norms in fp64 ----------
__global__ __launch_bounds__(256) void norm_kernel(const float* __restrict__ Wdec,
                                                   double* __restrict__ g64, float* __restrict__ g32) {
  __shared__ double lds[4];
  int j = blockIdx.x, t = threadIdx.x;
  float4 w = *(const float4*)(Wdec + (size_t)j * D_MODEL + t * 4);
  double a = (double)w.x * w.x + (double)w.y * w.y + (double)w.z * w.z + (double)w.w * w.w;
  double sum = blockReduceSum256(a, lds);
  if (t == 0) { double g = sqrt(sum); g64[j] = g; g32[j] = (float)g; }
}

// ---------- pre-split W_enc fp32 -> tiled bf16 hi/lo [nt][ks][kc][c][e] ----------
__global__ __launch_bounds__(256) void wsplit_kernel(const float* __restrict__ Wenc,
                                                     short* __restrict__ Whi, short* __restrict__ Wlo) {
  __shared__ short sh[4096];
  __shared__ short sl[4096];
  int blk = blockIdx.x;            // 4096 = 128 nt * 32 ks
  int nt = blk >> 5, ks = blk & 31;
  int t = threadIdx.x;
  int r = t >> 3;                  // k within step, 0..31
  int cg = t & 7;                  // column sub-lane
  int kc = r >> 3, e = r & 7;
  const float* src = Wenc + (size_t)(ks * 32 + r) * D_SAE + nt * 128 + cg;
#pragma unroll
  for (int j = 0; j < 16; ++j) {
    float f = src[j * 8];
    unsigned short hh = f2bf(f);
    short ll = (short)f2bf(f - bf2f(hh));
    int c = j * 8 + cg;
    sh[kc * 1024 + c * 8 + e] = (short)hh;
    sl[kc * 1024 + c * 8 + e] = ll;
  }
  __syncthreads();
  size_t obase = ((size_t)nt * 32 + ks) * 4096;
  *(float4*)&Whi[obase + t * 16]     = *(const float4*)&sh[t * 16];
  *(float4*)&Whi[obase + t * 16 + 8] = *(const float4*)&sh[t * 16 + 8];
  *(float4*)&Wlo[obase + t * 16]     = *(const float4*)&sl[t * 16];
  *(float4*)&Wlo[obase + t * 16 + 8] = *(const float4*)&sl[t * 16 + 8];
}

// ---------- hi-only subsampled hist GEMM (big path): 128^2 tile, rows 0..511 ----------
__global__ __launch_bounds__(256) void hist_gemm(
    const short* __restrict__ Whi, const short* __restrict__ Ahi,
    const float* __restrict__ benc, const float* __restrict__ g32,
    int* __restrict__ ghist) {
  __shared__ short sA[4096];
  __shared__ short sB[4096];
  __shared__ int h[2048];
  const int tid = threadIdx.x;
  const int lane = tid & 63;
  const int w = tid >> 6;
  const int wm = (w >> 1) * 64, wn = (w & 1) * 64;
  int lin = blockIdx.x;            // 512 = 4 mt * 128 nt
  int mt = lin >> 7, nt = lin & 127;
  const int col0 = nt * 128;
  for (int i = tid; i < 2048; i += 256) h[i] = 0;
  const size_t atile = (size_t)mt * 131072;
  const size_t btile = (size_t)nt * 131072;
  f32x4 acc[4][4] = {};
  const int kcl = lane >> 4, l15 = lane & 15;

  float4 a0, a1, b0, b1;
  {
    const float4* ah4 = (const float4*)(Ahi + atile);
    const float4* bh4 = (const float4*)(Whi + btile);
    a0 = ah4[tid]; a1 = ah4[tid + 256];
    b0 = bh4[tid]; b1 = bh4[tid + 256];
  }
  for (int ks = 0; ks < 32; ++ks) {
    __syncthreads();
    *(float4*)&sA[(size_t)tid * 8] = a0;
    *(float4*)&sA[(size_t)(tid + 256) * 8] = a1;
    *(float4*)&sB[(size_t)tid * 8] = b0;
    *(float4*)&sB[(size_t)(tid + 256) * 8] = b1;
    __syncthreads();
    if (ks < 31) {
      const float4* ah4 = (const float4*)(Ahi + atile + (ks + 1) * 4096);
      const float4* bh4 = (const float4*)(Whi + btile + (ks + 1) * 4096);
      a0 = ah4[tid]; a1 = ah4[tid + 256];
      b0 = bh4[tid]; b1 = bh4[tid + 256];
    }
    bf16x8 ahf[4];
#pragma unroll
    for (int fm = 0; fm < 4; ++fm)
      ahf[fm] = *(const bf16x8*)&sA[(kcl * 128 + wm + fm * 16 + l15) * 8];
#pragma unroll
    for (int fn = 0; fn < 4; ++fn) {
      bf16x8 bh = *(const bf16x8*)&sB[(kcl * 128 + wn + fn * 16 + l15) * 8];
#pragma unroll
      for (int fm = 0; fm < 4; ++fm)
        acc[fm][fn] = __builtin_amdgcn_mfma_f32_16x16x32_bf16(ahf[fm], bh, acc[fm][fn], 0, 0, 0);
    }
  }
#pragma unroll
  for (int fn = 0; fn < 4; ++fn) {
    int col = col0 + wn + fn * 16 + l15;
    float g = g32[col], be = benc[col];
#pragma unroll
    for (int fm = 0; fm < 4; ++fm) {
#pragma unroll
      for (int r = 0; r < 4; ++r) {
        float z = acc[fm][fn][r] + be;
        float s = z > 0.f ? z * g : 0.f;
        unsigned bits = __float_as_uint(s);
        if (bits) atomicAdd(&h[bits >> 21], 1);
      }
    }
  }
  __syncthreads();
  for (int i = tid; i < 2048; i += 256)
    if (h[i]) atomicAdd(&ghist[i], h[i]);
}

// ---------- 256x256 split-bf16 MFMA extract GEMM (big path) ----------
// 512 thr / 8 waves (2m x 4n), BK=32, reg-prefetch, B-frags held, A-frags streamed.
__global__ __launch_bounds__(512) void mfma_gemm256(
    const short* __restrict__ Whi, const short* __restrict__ Wlo,
    const short* __restrict__ Ahi, const short* __restrict__ Alo,
    const float* __restrict__ benc, const float* __restrict__ g32,
    int* __restrict__ ctrl, int* __restrict__ cand_idx, float* __restrict__ cand_sc) {
  __shared__ short sA[16384];   // hi [4][256][8] | lo at +8192
  __shared__ short sB[16384];
  __shared__ int h[2];

  const int tid = threadIdx.x;         // 0..511
  const int lane = tid & 63;
  const int w = tid >> 6;              // 0..7
  const int wm = (w >> 2) * 128;       // 0 / 128
  const int wn = (w & 3) * 64;         // 0..192

  int lin = blockIdx.x;                // 1024 blocks
  int xcd = lin & 7, j = lin >> 3;     // j 0..127
  int mt2 = j & 15;                    // 16 x 256-row tiles
  int nt2 = (xcd << 3) | (j >> 4);     // 64 x 256-col tiles; XCD owns 8 panels
  const int row0 = mt2 * 256, col0 = nt2 * 256;
  if (tid == 0) h[0] = 0;

  const size_t at0 = (size_t)(mt2 * 2) * 131072, at1 = at0 + 131072;
  const size_t bt0 = (size_t)(nt2 * 2) * 131072, bt1 = bt0 + 131072;
  const int dkc = tid >> 7, dml = tid & 127;            // stage dest decode
  const int dst = (dkc * 256 + dml) * 8;                // sub0 dest
  const int dst1 = dst + 128 * 8;                       // sub1 dest (+128 rows)

  f32x4 acc[8][4] = {};
  const int kcl = lane >> 4, l15 = lane & 15;

  float4 a0, a1, a2, a3, b0, b1, b2, b3;
  {
    a0 = ((const float4*)(Ahi + at0))[tid]; a1 = ((const float4*)(Ahi + at1))[tid];
    a2 = ((const float4*)(Alo + at0))[tid]; a3 = ((const float4*)(Alo + at1))[tid];
    b0 = ((const float4*)(Whi + bt0))[tid]; b1 = ((const float4*)(Whi + bt1))[tid];
    b2 = ((const float4*)(Wlo + bt0))[tid]; b3 = ((const float4*)(Wlo + bt1))[tid];
  }

  for (int ks = 0; ks < 32; ++ks) {
    __syncthreads();   // previous tile fully consumed
    *(float4*)&sA[dst] = a0;  *(float4*)&sA[dst1] = a1;
    *(float4*)&sA[8192 + dst] = a2;  *(float4*)&sA[8192 + dst1] = a3;
    *(float4*)&sB[dst] = b0;  *(float4*)&sB[dst1] = b1;
    *(float4*)&sB[8192 + dst] = b2;  *(float4*)&sB[8192 + dst1] = b3;
    __syncthreads();   // tile visible
    if (ks < 31) {
      const int o = (ks + 1) * 4096;
      a0 = ((const float4*)(Ahi + at0 + o))[tid]; a1 = ((const float4*)(Ahi + at1 + o))[tid];
      a2 = ((const float4*)(Alo + at0 + o))[tid]; a3 = ((const float4*)(Alo + at1 + o))[tid];
      b0 = ((const float4*)(Whi + bt0 + o))[tid]; b1 = ((const float4*)(Whi + bt1 + o))[tid];
      b2 = ((const float4*)(Wlo + bt0 + o))[tid]; b3 = ((const float4*)(Wlo + bt1 + o))[tid];
    }
    bf16x8 bh[4], bl[4];
#pragma unroll
    for (int fn = 0; fn < 4; ++fn) {
      int boff = (kcl * 256 + wn + fn * 16 + l15) * 8;
      bh[fn] = *(const bf16x8*)&sB[boff];
      bl[fn] = *(const bf16x8*)&sB[8192 + boff];
    }
#pragma unroll
    for (int fm = 0; fm < 8; ++fm) {
      int aoff = (kcl * 256 + wm + fm * 16 + l15) * 8;
      bf16x8 ah = *(const bf16x8*)&sA[aoff];
      bf16x8 al = *(const bf16x8*)&sA[8192 + aoff];
#pragma unroll
      for (int fn = 0; fn < 4; ++fn) {
        acc[fm][fn] = __builtin_amdgcn_mfma_f32_16x16x32_bf16(ah, bh[fn], acc[fm][fn], 0, 0, 0);
        acc[fm][fn] = __builtin_amdgcn_mfma_f32_16x16x32_bf16(al, bh[fn], acc[fm][fn], 0, 0, 0);
        acc[fm][fn] = __builtin_amdgcn_mfma_f32_16x16x32_bf16(ah, bl[fn], acc[fm][fn], 0, 0, 0);
      }
    }
  }

  // epilogue: C col=lane&15, row=(lane>>4)*4+r; block-aggregated append
  const int l4r = lane >> 4;
  unsigned thrBits = (unsigned)ctrl[1];
  int cnt = 0;
#pragma unroll
  for (int fn = 0; fn < 4; ++fn) {
    int col = col0 + wn + fn * 16 + l15;
    float g = g32[col], be = benc[col];
#pragma unroll
    for (int fm = 0; fm < 8; ++fm) {
#pragma unroll
      for (int r = 0; r < 4; ++r) {
        float z = acc[fm][fn][r] + be;
        float s = z > 0.f ? z * g : 0.f;
        cnt += (__float_as_uint(s) >= thrBits) ? 1 : 0;
      }
    }
  }
  int my = 0;
  if (cnt) my = atomicAdd(&h[0], cnt);
  __syncthreads();
  if (tid == 0) h[1] = atomicAdd(&ctrl[2], h[0]);
  __syncthreads();
  int pos = h[1] + my;
#pragma unroll
  for (int fn = 0; fn < 4; ++fn) {
    int col = col0 + wn + fn * 16 + l15;
    float g = g32[col], be = benc[col];
#pragma unroll
    for (int fm = 0; fm < 8; ++fm) {
      int rowb = row0 + wm + fm * 16 + l4r * 4;
#pragma unroll
      for (int r = 0; r < 4; ++r) {
        float z = acc[fm][fn][r] + be;
        float s = z > 0.f ? z * g : 0.f;
        if (__float_as_uint(s) >= thrBits) {
          if (pos < CAND_CAP) { cand_idx[pos] = (rowb + r) * D_SAE + col; cand_sc[pos] = s; }
          pos++;
        }
      }
    }
  }
}

// ---------- fallback 128^2 GEMM (small ws): MODE 0 = hist (1/16), MODE 1 = extract ----------
template <int MODE>
__global__ __launch_bounds__(256) void mfma_gemm(
    const float* __restrict__ Wenc,
    const short* __restrict__ Ahi, const short* __restrict__ Alo,
    const float* __restrict__ benc, const float* __restrict__ g32,
    int* __restrict__ ghist, int* __restrict__ ctrl,
    int* __restrict__ cand_idx, float* __restrict__ cand_sc) {
  __shared__ short sA[8192];
  __shared__ short sB[8192];
  __shared__ int h[(MODE == 0) ? 2048 : 2];
  const int tid = threadIdx.x;
  const int lane = tid & 63;
  const int w = tid >> 6;
  const int wm = (w >> 1) * 64, wn = (w & 1) * 64;
  int lin = blockIdx.x;
  int mt, nt;
  if (MODE == 0) { mt = lin >> 7; nt = lin & 127; }
  else { int xcd = lin & 7, j = lin >> 3; mt = j & 31; nt = (xcd << 4) | (j >> 5); }
  const int row0 = mt * 128, col0 = nt * 128;
  if (MODE == 0) { for (int i = tid; i < 2048; i += 256) h[i] = 0; }
  else if (tid == 0) h[0] = 0;
  const int nl = tid & 127;
  const int half = tid >> 7;
  const float* wbase = Wenc + (size_t)col0 + nl;
  const size_t atile = (size_t)mt * 131072;
  f32x4 acc[4][4] = {};
  const int kcl = lane >> 4, l15 = lane & 15;
  float4 a0, a1, a2, a3;
  float bfv[16];
  {
    const float4* ah4 = (const float4*)(Ahi + atile);
    const float4* al4 = (const float4*)(Alo + atile);
    a0 = ah4[tid]; a1 = ah4[tid + 256];
    a2 = al4[tid]; a3 = al4[tid + 256];
#pragma unroll
    for (int p = 0; p < 4; ++p)
#pragma unroll
      for (int i = 0; i < 4; ++i)
        bfv[p * 4 + i] = wbase[(size_t)(p * 8 + half * 4 + i) * D_SAE];
  }
  for (int ks = 0; ks < 32; ++ks) {
    short hb[16], lb[16];
#pragma unroll
    for (int q = 0; q < 16; ++q) {
      unsigned short hh = f2bf(bfv[q]);
      hb[q] = (short)hh;
      lb[q] = (short)f2bf(bfv[q] - bf2f(hh));
    }
    __syncthreads();
    *(float4*)&sA[(size_t)tid * 8] = a0;
    *(float4*)&sA[(size_t)(tid + 256) * 8] = a1;
    *(float4*)&sA[(size_t)(512 + tid) * 8] = a2;
    *(float4*)&sA[(size_t)(512 + tid + 256) * 8] = a3;
#pragma unroll
    for (int p = 0; p < 4; ++p) {
      int boff = p * 1024 + nl * 8 + half * 4;
      *(short4*)&sB[boff] = make_short4(hb[p * 4], hb[p * 4 + 1], hb[p * 4 + 2], hb[p * 4 + 3]);
      *(short4*)&sB[4096 + boff] = make_short4(lb[p * 4], lb[p * 4 + 1], lb[p * 4 + 2], lb[p * 4 + 3]);
    }
    __syncthreads();
    if (ks < 31) {
      const float4* ah4 = (const float4*)(Ahi + atile + (ks + 1) * 4096);
      const float4* al4 = (const float4*)(Alo + atile + (ks + 1) * 4096);
      a0 = ah4[tid]; a1 = ah4[tid + 256];
      a2 = al4[tid]; a3 = al4[tid + 256];
      const int k0n = (ks + 1) * 32;
#pragma unroll
      for (int p = 0; p < 4; ++p)
#pragma unroll
        for (int i = 0; i < 4; ++i)
          bfv[p * 4 + i] = wbase[(size_t)(k0n + p * 8 + half * 4 + i) * D_SAE];
    }
    bf16x8 ahf[4], alf[4];
#pragma unroll
    for (int fm = 0; fm < 4; ++fm) {
      int off = (kcl * 128 + wm + fm * 16 + l15) * 8;
      ahf[fm] = *(const bf16x8*)&sA[off];
      alf[fm] = *(const bf16x8*)&sA[4096 + off];
    }
#pragma unroll
    for (int fn = 0; fn < 4; ++fn) {
      int boff = (kcl * 128 + wn + fn * 16 + l15) * 8;
      bf16x8 bh = *(const bf16x8*)&sB[boff];
      bf16x8 bl = *(const bf16x8*)&sB[4096 + boff];
#pragma unroll
      for (int fm = 0; fm < 4; ++fm) {
        acc[fm][fn] = __builtin_amdgcn_mfma_f32_16x16x32_bf16(ahf[fm], bh, acc[fm][fn], 0, 0, 0);
        acc[fm][fn] = __builtin_amdgcn_mfma_f32_16x16x32_bf16(alf[fm], bh, acc[fm][fn], 0, 0, 0);
        acc[fm][fn] = __builtin_amdgcn_mfma_f32_16x16x32_bf16(ahf[fm], bl, acc[fm][fn], 0, 0, 0);
      }
    }
  }
  const int l4r = lane >> 4;
  if (MODE == 0) {
#pragma unroll
    for (int fn = 0; fn < 4; ++fn) {
      int col = col0 + wn + fn * 16 + l15;
      float g = g32[col], be = benc[col];
#pragma unroll
      for (int fm = 0; fm < 4; ++fm) {
#pragma unroll
        for (int r = 0; r < 4; ++r) {
          float z = acc[fm][fn][r] + be;
          float s = z > 0.f ? z * g : 0.f;
          unsigned bits = __float_as_uint(s);
          if (bits) atomicAdd(&h[bits >> 21], 1);
        }
      }
    }
    __syncthreads();
    for (int i = tid; i < 2048; i += 256)
      if (h[i]) atomicAdd(&ghist[i], h[i]);
  } else {
    unsigned thrBits = (unsigned)ctrl[1];
    int cnt = 0;
#pragma unroll
    for (int fn = 0; fn < 4; ++fn) {
      int col = col0 + wn + fn * 16 + l15;
      float g = g32[col], be = benc[col];
#pragma unroll
      for (int fm = 0; fm < 4; ++fm) {
#pragma unroll
        for (int r = 0; r < 4; ++r) {
          float z = acc[fm][fn][r] + be;
          float s = z > 0.f ? z * g : 0.f;
          cnt += (__float_as_uint(s) >= thrBits) ? 1 : 0;
        }
      }
    }
    int my = 0;
    if (cnt) my = atomicAdd(&h[0], cnt);
    __syncthreads();
    if (tid == 0) h[1] = atomicAdd(&ctrl[2], h[0]);
    __syncthreads();
    int pos = h[1] + my;
#pragma unroll
    for (int fn = 0; fn < 4; ++fn) {
      int col = col0 + wn + fn * 16 + l15;
      float g = g32[col], be = benc[col];
#pragma unroll
      for (int fm = 0; fm < 4; ++fm) {
        int rowb = row0 + wm + fm * 16 + l4r * 4;
#pragma unroll
        for (int r = 0; r < 4; ++r) {
          float z = acc[fm][fn][r] + be;
          float s = z > 0.f ? z * g : 0.f;
          if (__float_as_uint(s) >= thrBits) {
            if (pos < CAND_CAP) { cand_idx[pos] = (rowb + r) * D_SAE + col; cand_sc[pos] = s; }
            pos++;
          }
        }
      }
    }
  }
}

// ---------- coarse threshold from 1/sub-subsampled hist, with margins ----------
__global__ void find_coarse_kernel(const int* __restrict__ gh, int* ctrl,
                                   const int* __restrict__ kptr, int sub) {
  if (threadIdx.x || blockIdx.x) return;
  long long kB = (long long)kptr[0] * BATCH;
  long long need_samp = (kB + 500000 + sub - 1) / sub;     // full-scale est >= kB+500K
  long long floor_samp = 720000 / sub;
  if (need_samp < floor_samp) need_samp = floor_samp;
  long long cum = 0;
  int b = 2047;
  for (; b > 0; b--) {
    long long c = gh[b];
    if (cum + c >= need_samp) break;
    cum += c;
  }
  long long est_incl = (long long)sub * (cum + gh[b]);
  if (est_incl > 3500000LL && (long long)sub * cum >= kB + 120000LL) b = b + 1;
  ctrl[1] = (int)(((unsigned)b) << 21);
}

// ---------- radix histograms over candidate scores ----------
__global__ __launch_bounds__(256) void chist_kernel(const float* __restrict__ cand_sc,
                                                    const int* __restrict__ ctrl,
                                                    int* __restrict__ ghist, int pass) {
  __shared__ int h[2048];
  int nb = (pass == 2) ? 1024 : 2048;
  for (int i = threadIdx.x; i < nb; i += 256) h[i] = 0;
  __syncthreads();
  int n = ctrl[2]; if (n > CAND_CAP) n = CAND_CAP;
  unsigned sel1 = 0, sel22 = 0;
  if (pass == 1) sel1 = (unsigned)ctrl[3];
  if (pass == 2) sel22 = ((unsigned)ctrl[3] << 11) | (unsigned)ctrl[5];
  for (int i = blockIdx.x * 256 + threadIdx.x; i < n; i += gridDim.x * 256) {
    unsigned bits = __float_as_uint(cand_sc[i]);
    if (pass == 0) atomicAdd(&h[bits >> 21], 1);
    else if (pass == 1) { if ((bits >> 21) == sel1) atomicAdd(&h[(bits >> 10) & 0x7FFu], 1); }
    else { if ((bits >> 10) == sel22) atomicAdd(&h[bits & 0x3FFu], 1); }
  }
  __syncthreads();
  for (int i = threadIdx.x; i < nb; i += 256)
    if (h[i]) atomicAdd(&ghist[i], h[i]);
}

__global__ void cfind_kernel(const int* __restrict__ hist, int* ctrl,
                             const int* __restrict__ kptr, int pass) {
  if (threadIdx.x || blockIdx.x) return;
  int kB = kptr[0] * BATCH;
  int need, nbins;
  if (pass == 0)      { need = kB;                       nbins = 2048; }
  else if (pass == 1) { need = kB - ctrl[4];             nbins = 2048; }
  else                { need = kB - ctrl[4] - ctrl[6];   nbins = 1024; }
  int cum = 0, b = nbins - 1;
  for (; b > 0; b--) {
    int c = hist[b];
    if (cum + c >= need) break;
    cum += c;
  }
  if (pass == 0)      { ctrl[3] = b; ctrl[4] = cum; }
  else if (pass == 1) { ctrl[5] = b; ctrl[6] = cum; }
  else {
    unsigned vbits = ((unsigned)ctrl[3] << 21) | ((unsigned)ctrl[5] << 10) | (unsigned)b;
    float V = __uint_as_float(vbits);
    float* cf = (float*)ctrl;
    cf[8] = V; cf[9] = V + EPS_M; cf[10] = V - EPS_M;
  }
}

// ---------- band partition ----------
__global__ __launch_bounds__(256) void band_kernel(const int* __restrict__ cand_idx,
    const float* __restrict__ cand_sc, const float* __restrict__ g32,
    int* ctrl, int* row_cnt, int* row_feat, float* row_act, int* cand2_idx) {
  const float* cf = (const float*)ctrl;
  float hi = cf[9], lo = cf[10];
  int n = ctrl[2]; if (n > CAND_CAP) n = CAND_CAP;
  int lane = threadIdx.x & 63;
  int defc = 0;
  for (int i = blockIdx.x * 256 + threadIdx.x; i < n; i += gridDim.x * 256) {
    float s = cand_sc[i];
    int flat = cand_idx[i];
    if (s > hi) {
      int b = flat >> 14, j = flat & (D_SAE - 1);
      int p = atomicAdd(&row_cnt[b], 1);
      if (p < ROW_CAP) { row_feat[b * ROW_CAP + p] = j; row_act[b * ROW_CAP + p] = s / g32[j]; }
      defc++;
    }
    bool isc = (s <= hi) && (s >= lo);
    int pos = wave_append(isc, &ctrl[12]);
    if (isc && pos >= 0 && pos < CAND2_CAP) cand2_idx[pos] = flat;
  }
#pragma unroll
  for (int off = 32; off > 0; off >>= 1) defc += __shfl_down(defc, off, 64);
  if (lane == 0 && defc) atomicAdd(&ctrl[11], defc);
}

// ---------- fp64 rescore of band candidates ----------
__global__ __launch_bounds__(256) void cand2_score_kernel(const int* __restrict__ ctrl,
    const int* __restrict__ cand2_idx, const float* __restrict__ x,
    const float* __restrict__ Wdec, const float* __restrict__ benc,
    const double* __restrict__ g64, double* __restrict__ cand2_sc) {
  __shared__ double lds[4];
  int n2 = ctrl[12]; if (n2 > CAND2_CAP) n2 = CAND2_CAP;
  int t = threadIdx.x;
  for (int c = blockIdx.x; c < n2; c += gridDim.x) {
    int flat = cand2_idx[c];
    int b = flat >> 14, j = flat & (D_SAE - 1);
    double d[4];
    ln_row_fp64(x + (size_t)b * (2 * D_MODEL), lds, d);
    float4 w4 = *(const float4*)(Wdec + (size_t)j * D_MODEL + t * 4);
    double a = d[0] * (double)w4.x + d[1] * (double)w4.y + d[2] * (double)w4.z + d[3] * (double)w4.w;
    double z = blockReduceSum256(a, lds) + (double)benc[j];
    double sc = z > 0 ? z * g64[j] : 0.0;
    if (t == 0) cand2_sc[c] = sc;
  }
}

// ---------- rank band candidates (fp64, index-stable), accept fill ----------
__global__ __launch_bounds__(256) void cand2_rank_kernel(const int* __restrict__ ctrl,
    const int* __restrict__ cand2_idx, const double* __restrict__ cand2_sc,
    const double* __restrict__ g64, const int* __restrict__ kptr,
    int* row_cnt, int* row_feat, float* row_act) {
  __shared__ int lds[4];
  int n2 = ctrl[12]; if (n2 > CAND2_CAP) n2 = CAND2_CAP;
  int kB = kptr[0] * BATCH;
  int fill = kB - ctrl[11];
  int t = threadIdx.x;
  for (int c = blockIdx.x; c < n2; c += gridDim.x) {
    double sc = cand2_sc[c];
    int fc = cand2_idx[c];
    int cnt = 0;
    for (int y = t; y < n2; y += 256) {
      double sy = cand2_sc[y];
      if (sy > sc || (sy == sc && cand2_idx[y] < fc)) cnt++;
    }
    cnt = blockReduceSumInt256(cnt, lds);
    if (t == 0 && cnt < fill) {
      int b = fc >> 14, j = fc & (D_SAE - 1);
      int p = atomicAdd(&row_cnt[b], 1);
      if (p < ROW_CAP) { row_feat[b * ROW_CAP + p] = j; row_act[b * ROW_CAP + p] = (float)(sc / g64[j]); }
    }
  }
}

// ---------- sparse recon (float4, 2-way ILP) ----------
__global__ __launch_bounds__(256) void recon_kernel(const int* __restrict__ row_cnt,
    const int* __restrict__ row_feat, const float* __restrict__ row_act,
    const float* __restrict__ Wdec, const float* __restrict__ bdec, float* __restrict__ out) {
  int b = blockIdx.x, t = threadIdx.x;
  float4 acc0 = *(const float4*)&bdec[t * 4];
  float4 acc1 = make_float4(0.f, 0.f, 0.f, 0.f);
  int n = row_cnt[b]; if (n > ROW_CAP) n = ROW_CAP;
  const int* rf = row_feat + (size_t)b * ROW_CAP;
  const float* ra = row_act + (size_t)b * ROW_CAP;
  int p = 0;
  for (; p + 2 <= n; p += 2) {
    int j0 = rf[p], j1 = rf[p + 1];
    float v0 = ra[p], v1 = ra[p + 1];
    float4 w0 = *(const float4*)(Wdec + (size_t)j0 * D_MODEL + t * 4);
    float4 w1 = *(const float4*)(Wdec + (size_t)j1 * D_MODEL + t * 4);
    acc0.x += v0 * w0.x; acc0.y += v0 * w0.y; acc0.z += v0 * w0.z; acc0.w += v0 * w0.w;
    acc1.x += v1 * w1.x; acc1.y += v1 * w1.y; acc1.z += v1 * w1.z; acc1.w += v1 * w1.w;
  }
  if (p < n) {
    int j0 = rf[p]; float v0 = ra[p];
    float4 w0 = *(const float4*)(Wdec + (size_t)j0 * D_MODEL + t * 4);
    acc0.x += v0 * w0.x; acc0.y += v0 * w0.y; acc0.z += v0 * w0.z; acc0.w += v0 * w0.w;
  }
  acc0.x += acc1.x; acc0.y += acc1.y; acc0.z += acc1.z; acc0.w += acc1.w;
  *(float4*)(out + (size_t)b * D_MODEL + t * 4) = acc0;
}

extern "C" void kernel_launch(void* const* d_in, const int* in_sizes, int n_in,
                              void* d_out, int out_size, void* d_ws, size_t ws_size,
                              hipStream_t stream) {
  const float* x    = (const float*)d_in[0];
  const float* Wenc = (const float*)d_in[1];
  const float* benc = (const float*)d_in[2];
  const float* Wdec = (const float*)d_in[3];
  const float* bdec = (const float*)d_in[4];
  const int*   kptr = (const int*)d_in[5];
  float* out = (float*)d_out;

  char* ws = (char*)d_ws;
  size_t off = 0;
  short*  Ahi       = (short*)(ws + off);  off += (size_t)BATCH * D_MODEL * 2;
  short*  Alo       = (short*)(ws + off);  off += (size_t)BATCH * D_MODEL * 2;
  int*    cand_idx  = (int*)(ws + off);    off += (size_t)CAND_CAP * 4;
  float*  cand_sc   = (float*)(ws + off);  off += (size_t)CAND_CAP * 4;
  int*    row_feat  = (int*)(ws + off);    off += (size_t)BATCH * ROW_CAP * 4;
  float*  row_act   = (float*)(ws + off);  off += (size_t)BATCH * ROW_CAP * 4;
  int*    cand2_idx = (int*)(ws + off);    off += (size_t)CAND2_CAP * 4;
  double* cand2_sc  = (double*)(ws + off); off += (size_t)CAND2_CAP * 8;
  double* g64       = (double*)(ws + off); off += (size_t)D_SAE * 8;
  float*  g32       = (float*)(ws + off);  off += (size_t)D_SAE * 4;
  char*   zbase     = ws + off;
  int* ghist   = (int*)(zbase);
  int* h1      = (int*)(zbase + 8192);
  int* h2      = (int*)(zbase + 16384);
  int* h3      = (int*)(zbase + 24576);
  int* ctrl    = (int*)(zbase + 28672);
  int* row_cnt = (int*)(zbase + 28928);
  size_t zbytes = 28928 + (size_t)BATCH * 4;
  size_t small_need = off + zbytes;
  if (small_need > ws_size) return;  // ~60 MB floor

  size_t big_off = (small_need + 255) & ~(size_t)255;
  short* Whi = (short*)(ws + big_off);
  short* Wlo = Whi + (size_t)D_MODEL * D_SAE;
  size_t big_need = big_off + (size_t)D_MODEL * D_SAE * 4;
  const bool big = (big_need <= ws_size);   // round-6-proven to fit

  hipMemsetAsync(zbase, 0, zbytes, stream);

  ln_kernel<<<BATCH, 256, 0, stream>>>(x, Ahi, Alo);
  norm_kernel<<<D_SAE, 256, 0, stream>>>(Wdec, g64, g32);
  if (big) {
    wsplit_kernel<<<4096, 256, 0, stream>>>(Wenc, Whi, Wlo);
    hist_gemm<<<512, 256, 0, stream>>>(Whi, Ahi, benc, g32, ghist);
    find_coarse_kernel<<<1, 1, 0, stream>>>(ghist, ctrl, kptr, 8);
    mfma_gemm256<<<1024, 512, 0, stream>>>(Whi, Wlo, Ahi, Alo, benc, g32, ctrl, cand_idx, cand_sc);
  } else {
    mfma_gemm<0><<<256, 256, 0, stream>>>(Wenc, Ahi, Alo, benc, g32, ghist, ctrl, nullptr, nullptr);
    find_coarse_kernel<<<1, 1, 0, stream>>>(ghist, ctrl, kptr, 16);
    mfma_gemm<1><<<4096, 256, 0, stream>>>(Wenc, Ahi, Alo, benc, g32, nullptr, ctrl, cand_idx, cand_sc);
  }
  chist_kernel<<<1024, 256, 0, stream>>>(cand_sc, ctrl, h1, 0);
  cfind_kernel<<<1, 1, 0, stream>>>(h1, ctrl, kptr, 0);
  chist_kernel<<<1024, 256, 0, stream>>>(cand_sc, ctrl, h2, 1);
  cfind_kernel<<<1, 1, 0, stream>>>(h2, ctrl, kptr, 1);
  chist_kernel<<<1024, 256, 0, stream>>>(cand_sc, ctrl, h3, 2);
  cfind_kernel<<<1, 1, 0, stream>>>(h3, ctrl, kptr, 2);
  band_kernel<<<1024, 256, 0, stream>>>(cand_idx, cand_sc, g32, ctrl, row_cnt, row_feat, row_act, cand2_idx);
  cand2_score_kernel<<<4096, 256, 0, stream>>>(ctrl, cand2_idx, x, Wdec, benc, g64, cand2_sc);
  cand2_rank_kernel<<<2048, 256, 0, stream>>>(ctrl, cand2_idx, cand2_sc, g64, kptr, row_cnt, row_feat, row_act);
  recon_kernel<<<BATCH, 256, 0, stream>>>(row_cnt, row_feat, row_act, Wdec, bdec, out);
}

// Round 9
// 754.445 us; speedup vs baseline: 9.0871x; 1.6407x over previous
//
#include <hip/hip_runtime.h>
#include <math.h>

#define D_MODEL 1024
#define D_SAE   16384
#define BATCH   4096
#define NTOT    (1ull * BATCH * D_SAE)
#define LN_EPS  1e-8
#define EPS_M   3e-4f        // |split-bf16 score - fp64 score| safe band half-width (>=6x margin)
#define ROW_CAP 256
#define CAND_CAP  (4 * 1024 * 1024)
#define CAND2_CAP 65536

using bf16x8 = __attribute__((ext_vector_type(8))) short;
using f32x4  = __attribute__((ext_vector_type(4))) float;

__device__ inline unsigned short f2bf(float f) {   // RNE fp32->bf16
  unsigned u = __float_as_uint(f);
  return (unsigned short)((u + 0x7fffu + ((u >> 16) & 1u)) >> 16);
}
__device__ inline float bf2f(unsigned short h) {
  return __uint_as_float((unsigned)h << 16);
}

// ---------- block (256-thread) reductions ----------
__device__ inline double blockReduceSum256(double v, double* lds) {
#pragma unroll
  for (int off = 32; off > 0; off >>= 1) v += __shfl_down(v, off, 64);
  int lane = threadIdx.x & 63, wid = threadIdx.x >> 6;
  __syncthreads();
  if (lane == 0) lds[wid] = v;
  __syncthreads();
  return lds[0] + lds[1] + lds[2] + lds[3];
}
__device__ inline int blockReduceSumInt256(int v, int* lds) {
#pragma unroll
  for (int off = 32; off > 0; off >>= 1) v += __shfl_down(v, off, 64);
  int lane = threadIdx.x & 63, wid = threadIdx.x >> 6;
  __syncthreads();
  if (lane == 0) lds[wid] = v;
  __syncthreads();
  return lds[0] + lds[1] + lds[2] + lds[3];
}

__device__ inline int wave_append(bool pred, int* counter) {
  unsigned long long m = __ballot(pred);
  int lane = threadIdx.x & 63;
  int pos = -1;
  if (m) {
    int ldr = __ffsll((long long)m) - 1;
    int base = 0;
    if (lane == ldr) base = atomicAdd(counter, __popcll(m));
    base = __shfl(base, ldr, 64);
    if (pred) pos = base + __popcll(m & ((1ull << lane) - 1ull));
  }
  return pos;
}

// ---------- 64-lane parallel descending histogram scan ----------
// Semantics identical to: for(b=nbins-1;b>0;b--){c=hist[b]; if(cum+c>=need)break; cum+=c;}
__device__ inline void hist_scan_desc(const int* __restrict__ hist, int nbins, int need,
                                      int& bsel, int& cumsel) {
  int t = threadIdx.x;          // 0..63
  int chunk = nbins >> 6;
  int topbase = nbins - t * chunk;   // exclusive top of this thread's chunk
  int psum = 0;
  for (int i = 1; i <= chunk; ++i) psum += hist[topbase - i];
  int incl = psum;
#pragma unroll
  for (int off = 1; off < 64; off <<= 1) {
    int v = __shfl_up(incl, off, 64);
    if (t >= off) incl += v;
  }
  int excl = incl - psum;       // count in bins strictly above this chunk
  bool hit = (excl < need) && (excl + psum >= need);
  unsigned long long m = __ballot(hit);
  int tb = m ? (__ffsll((long long)m) - 1) : 63;
  int exb = __shfl(excl, tb, 64);
  int res_b = 0, res_c = 0;
  if (t == tb) {
    int c = exb;
    int b = nbins - tb * chunk - 1;
    int bend = b - chunk;       // exclusive lower limit
    for (; b > 0 && b > bend; --b) {
      int cc = hist[b];
      if (c + cc >= need) break;
      c += cc;
    }
    res_b = b; res_c = c;
  }
  bsel = __shfl(res_b, tb, 64);
  cumsel = __shfl(res_c, tb, 64);
}

// ---------- per-thread fp64 LN chain: thread t owns elements t*4..t*4+3 ----------
__device__ inline void ln_row_fp64(const float* __restrict__ row, double* lds, double d[4]) {
  int t = threadIdx.x;
  float4 s4 = *(const float4*)(row + t * 4);
  float4 t4 = *(const float4*)(row + D_MODEL + t * 4);
  double s[4] = {s4.x, s4.y, s4.z, s4.w};
  double tt[4] = {t4.x, t4.y, t4.z, t4.w};
  double ms = blockReduceSum256(s[0] + s[1] + s[2] + s[3], lds) / D_MODEL;
  double mt = blockReduceSum256(tt[0] + tt[1] + tt[2] + tt[3], lds) / D_MODEL;
  double vs = 0, vt = 0;
#pragma unroll
  for (int i = 0; i < 4; i++) { double a = s[i] - ms; vs += a * a; a = tt[i] - mt; vt += a * a; }
  vs = blockReduceSum256(vs, lds) / D_MODEL;
  vt = blockReduceSum256(vt, lds) / D_MODEL;
  double rs = sqrt(vs + LN_EPS), rt = sqrt(vt + LN_EPS);
  double u[4];
#pragma unroll
  for (int i = 0; i < 4; i++) u[i] = (tt[i] - mt) / rt - (s[i] - ms) / rs;
  double mu = blockReduceSum256(u[0] + u[1] + u[2] + u[3], lds) / D_MODEL;
  double vu = 0;
#pragma unroll
  for (int i = 0; i < 4; i++) { double a = u[i] - mu; vu += a * a; }
  vu = blockReduceSum256(vu, lds) / D_MODEL;
  double ru = sqrt(vu + LN_EPS);
#pragma unroll
  for (int i = 0; i < 4; i++) d[i] = (u[i] - mu) / ru;
}

// ---------- LN -> split-bf16 A in GEMM-tiled layout [mt][ks][kc][ml][e] ----------
__global__ __launch_bounds__(256) void ln_kernel(const float* __restrict__ x,
                                                 short* __restrict__ Ahi, short* __restrict__ Alo) {
  __shared__ double lds[4];
  int b = blockIdx.x, t = threadIdx.x;
  double d[4];
  ln_row_fp64(x + (size_t)b * (2 * D_MODEL), lds, d);
  int mt = b >> 7, ml = b & 127;
  int ks = t >> 3, kc = (t >> 1) & 3, e0 = (t & 1) * 4;
  size_t base = ((((size_t)mt * 32 + ks) * 4 + kc) * 128 + ml) * 8 + e0;
  short h[4], l[4];
#pragma unroll
  for (int i = 0; i < 4; i++) {
    float f = (float)d[i];
    unsigned short hh = f2bf(f);
    h[i] = (short)hh;
    l[i] = (short)f2bf(f - bf2f(hh));
  }
  *(short4*)&Ahi[base] = make_short4(h[0], h[1], h[2], h[3]);
  *(short4*)&Alo[base] = make_short4(l[0], l[1], l[2], l[3]);
}

// ---------- dec_norms in fp64 ----------
__global__ __launch_bounds__(256) void norm_kernel(const float* __restrict__ Wdec,
                                                   double* __restrict__ g64, float* __restrict__ g32) {
  __shared__ double lds[4];
  int j = blockIdx.x, t = threadIdx.x;
  float4 w = *(const float4*)(Wdec + (size_t)j * D_MODEL + t * 4);
  double a = (double)w.x * w.x + (double)w.y * w.y + (double)w.z * w.z + (double)w.w * w.w;
  double sum = blockReduceSum256(a, lds);
  if (t == 0) { double g = sqrt(sum); g64[j] = g; g32[j] = (float)g; }
}

// ---------- pre-split W_enc fp32 -> tiled bf16 hi/lo [nt][ks][kc][c][e] ----------
__global__ __launch_bounds__(256) void wsplit_kernel(const float* __restrict__ Wenc,
                                                     short* __restrict__ Whi, short* __restrict__ Wlo) {
  __shared__ short sh[4096];
  __shared__ short sl[4096];
  int blk = blockIdx.x;            // 4096 = 128 nt * 32 ks
  int nt = blk >> 5, ks = blk & 31;
  int t = threadIdx.x;
  int r = t >> 3;
  int cg = t & 7;
  int kc = r >> 3, e = r & 7;
  const float* src = Wenc + (size_t)(ks * 32 + r) * D_SAE + nt * 128 + cg;
#pragma unroll
  for (int j = 0; j < 16; ++j) {
    float f = src[j * 8];
    unsigned short hh = f2bf(f);
    short ll = (short)f2bf(f - bf2f(hh));
    int c = j * 8 + cg;
    sh[kc * 1024 + c * 8 + e] = (short)hh;
    sl[kc * 1024 + c * 8 + e] = ll;
  }
  __syncthreads();
  size_t obase = ((size_t)nt * 32 + ks) * 4096;
  *(float4*)&Whi[obase + t * 16]     = *(const float4*)&sh[t * 16];
  *(float4*)&Whi[obase + t * 16 + 8] = *(const float4*)&sh[t * 16 + 8];
  *(float4*)&Wlo[obase + t * 16]     = *(const float4*)&sl[t * 16];
  *(float4*)&Wlo[obase + t * 16 + 8] = *(const float4*)&sl[t * 16 + 8];
}

// ---------- hi-only subsampled hist GEMM (big path): per-wave privatized hist ----------
__global__ __launch_bounds__(256) void hist_gemm(
    const short* __restrict__ Whi, const short* __restrict__ Ahi,
    const float* __restrict__ benc, const float* __restrict__ g32,
    int* __restrict__ ghist) {
  __shared__ short sA[4096];
  __shared__ short sB[4096];
  __shared__ int h[4][2048];
  const int tid = threadIdx.x;
  const int lane = tid & 63;
  const int w = tid >> 6;
  const int wm = (w >> 1) * 64, wn = (w & 1) * 64;
  int lin = blockIdx.x;            // 512 = 4 mt * 128 nt
  int mt = lin >> 7, nt = lin & 127;
  const int col0 = nt * 128;
  for (int i = tid; i < 8192; i += 256) ((int*)h)[i] = 0;
  const size_t atile = (size_t)mt * 131072;
  const size_t btile = (size_t)nt * 131072;
  f32x4 acc[4][4] = {};
  const int kcl = lane >> 4, l15 = lane & 15;

  float4 a0, a1, b0, b1;
  {
    const float4* ah4 = (const float4*)(Ahi + atile);
    const float4* bh4 = (const float4*)(Whi + btile);
    a0 = ah4[tid]; a1 = ah4[tid + 256];
    b0 = bh4[tid]; b1 = bh4[tid + 256];
  }
  for (int ks = 0; ks < 32; ++ks) {
    __syncthreads();
    *(float4*)&sA[(size_t)tid * 8] = a0;
    *(float4*)&sA[(size_t)(tid + 256) * 8] = a1;
    *(float4*)&sB[(size_t)tid * 8] = b0;
    *(float4*)&sB[(size_t)(tid + 256) * 8] = b1;
    __syncthreads();
    if (ks < 31) {
      const float4* ah4 = (const float4*)(Ahi + atile + (ks + 1) * 4096);
      const float4* bh4 = (const float4*)(Whi + btile + (ks + 1) * 4096);
      a0 = ah4[tid]; a1 = ah4[tid + 256];
      b0 = bh4[tid]; b1 = bh4[tid + 256];
    }
    bf16x8 ahf[4];
#pragma unroll
    for (int fm = 0; fm < 4; ++fm)
      ahf[fm] = *(const bf16x8*)&sA[(kcl * 128 + wm + fm * 16 + l15) * 8];
#pragma unroll
    for (int fn = 0; fn < 4; ++fn) {
      bf16x8 bh = *(const bf16x8*)&sB[(kcl * 128 + wn + fn * 16 + l15) * 8];
#pragma unroll
      for (int fm = 0; fm < 4; ++fm)
        acc[fm][fn] = __builtin_amdgcn_mfma_f32_16x16x32_bf16(ahf[fm], bh, acc[fm][fn], 0, 0, 0);
    }
  }
#pragma unroll
  for (int fn = 0; fn < 4; ++fn) {
    int col = col0 + wn + fn * 16 + l15;
    float g = g32[col], be = benc[col];
#pragma unroll
    for (int fm = 0; fm < 4; ++fm) {
#pragma unroll
      for (int r = 0; r < 4; ++r) {
        float z = acc[fm][fn][r] + be;
        float s = z > 0.f ? z * g : 0.f;
        unsigned bits = __float_as_uint(s);
        if (bits) atomicAdd(&h[w][bits >> 21], 1);
      }
    }
  }
  __syncthreads();
  for (int i = tid; i < 2048; i += 256) {
    int v = h[0][i] + h[1][i] + h[2][i] + h[3][i];
    if (v) atomicAdd(&ghist[i], v);
  }
}

// ---------- 256x256 split-bf16 MFMA extract GEMM with fused pass-0 histogram ----------
__global__ __launch_bounds__(512) void mfma_gemm256(
    const short* __restrict__ Whi, const short* __restrict__ Wlo,
    const short* __restrict__ Ahi, const short* __restrict__ Alo,
    const float* __restrict__ benc, const float* __restrict__ g32,
    int* __restrict__ ctrl, int* __restrict__ cand_idx, float* __restrict__ cand_sc,
    int* __restrict__ ghist) {
  __shared__ short sA[16384];   // hi [4][256][8] | lo at +8192
  __shared__ short sB[16384];
  __shared__ int hh[2050];      // [0..2047] hist, [2048] count, [2049] base

  const int tid = threadIdx.x;         // 0..511
  const int lane = tid & 63;
  const int w = tid >> 6;
  const int wm = (w >> 2) * 128;
  const int wn = (w & 3) * 64;

  int lin = blockIdx.x;                // 1024 blocks
  int xcd = lin & 7, j = lin >> 3;
  int mt2 = j & 15;
  int nt2 = (xcd << 3) | (j >> 4);
  const int row0 = mt2 * 256, col0 = nt2 * 256;

  const size_t at0 = (size_t)(mt2 * 2) * 131072, at1 = at0 + 131072;
  const size_t bt0 = (size_t)(nt2 * 2) * 131072, bt1 = bt0 + 131072;
  const int dkc = tid >> 7, dml = tid & 127;
  const int dst = (dkc * 256 + dml) * 8;
  const int dst1 = dst + 128 * 8;

  f32x4 acc[8][4] = {};
  const int kcl = lane >> 4, l15 = lane & 15;

  float4 a0, a1, a2, a3, b0, b1, b2, b3;
  {
    a0 = ((const float4*)(Ahi + at0))[tid]; a1 = ((const float4*)(Ahi + at1))[tid];
    a2 = ((const float4*)(Alo + at0))[tid]; a3 = ((const float4*)(Alo + at1))[tid];
    b0 = ((const float4*)(Whi + bt0))[tid]; b1 = ((const float4*)(Whi + bt1))[tid];
    b2 = ((const float4*)(Wlo + bt0))[tid]; b3 = ((const float4*)(Wlo + bt1))[tid];
  }

  for (int ks = 0; ks < 32; ++ks) {
    __syncthreads();
    *(float4*)&sA[dst] = a0;  *(float4*)&sA[dst1] = a1;
    *(float4*)&sA[8192 + dst] = a2;  *(float4*)&sA[8192 + dst1] = a3;
    *(float4*)&sB[dst] = b0;  *(float4*)&sB[dst1] = b1;
    *(float4*)&sB[8192 + dst] = b2;  *(float4*)&sB[8192 + dst1] = b3;
    __syncthreads();
    if (ks < 31) {
      const int o = (ks + 1) * 4096;
      a0 = ((const float4*)(Ahi + at0 + o))[tid]; a1 = ((const float4*)(Ahi + at1 + o))[tid];
      a2 = ((const float4*)(Alo + at0 + o))[tid]; a3 = ((const float4*)(Alo + at1 + o))[tid];
      b0 = ((const float4*)(Whi + bt0 + o))[tid]; b1 = ((const float4*)(Whi + bt1 + o))[tid];
      b2 = ((const float4*)(Wlo + bt0 + o))[tid]; b3 = ((const float4*)(Wlo + bt1 + o))[tid];
    }
    bf16x8 bh[4], bl[4];
#pragma unroll
    for (int fn = 0; fn < 4; ++fn) {
      int boff = (kcl * 256 + wn + fn * 16 + l15) * 8;
      bh[fn] = *(const bf16x8*)&sB[boff];
      bl[fn] = *(const bf16x8*)&sB[8192 + boff];
    }
#pragma unroll
    for (int fm = 0; fm < 8; ++fm) {
      int aoff = (kcl * 256 + wm + fm * 16 + l15) * 8;
      bf16x8 ah = *(const bf16x8*)&sA[aoff];
      bf16x8 al = *(const bf16x8*)&sA[8192 + aoff];
#pragma unroll
      for (int fn = 0; fn < 4; ++fn) {
        acc[fm][fn] = __builtin_amdgcn_mfma_f32_16x16x32_bf16(ah, bh[fn], acc[fm][fn], 0, 0, 0);
        acc[fm][fn] = __builtin_amdgcn_mfma_f32_16x16x32_bf16(al, bh[fn], acc[fm][fn], 0, 0, 0);
        acc[fm][fn] = __builtin_amdgcn_mfma_f32_16x16x32_bf16(ah, bl[fn], acc[fm][fn], 0, 0, 0);
      }
    }
  }

  // epilogue: count + fused pass-0 LDS histogram, then block-aggregated append
  const int l4r = lane >> 4;
  unsigned thrBits = (unsigned)ctrl[1];
  for (int i = tid; i < 2050; i += 512) hh[i] = 0;
  __syncthreads();
  int cnt = 0;
#pragma unroll
  for (int fn = 0; fn < 4; ++fn) {
    int col = col0 + wn + fn * 16 + l15;
    float g = g32[col], be = benc[col];
#pragma unroll
    for (int fm = 0; fm < 8; ++fm) {
#pragma unroll
      for (int r = 0; r < 4; ++r) {
        float z = acc[fm][fn][r] + be;
        float s = z > 0.f ? z * g : 0.f;
        unsigned bits = __float_as_uint(s);
        if (bits >= thrBits) { cnt++; atomicAdd(&hh[bits >> 21], 1); }
      }
    }
  }
  int my = 0;
  if (cnt) my = atomicAdd(&hh[2048], cnt);
  __syncthreads();
  if (tid == 0) hh[2049] = atomicAdd(&ctrl[2], hh[2048]);
  for (int i = tid; i < 2048; i += 512)
    if (hh[i]) atomicAdd(&ghist[i], hh[i]);
  __syncthreads();
  int pos = hh[2049] + my;
#pragma unroll
  for (int fn = 0; fn < 4; ++fn) {
    int col = col0 + wn + fn * 16 + l15;
    float g = g32[col], be = benc[col];
#pragma unroll
    for (int fm = 0; fm < 8; ++fm) {
      int rowb = row0 + wm + fm * 16 + l4r * 4;
#pragma unroll
      for (int r = 0; r < 4; ++r) {
        float z = acc[fm][fn][r] + be;
        float s = z > 0.f ? z * g : 0.f;
        if (__float_as_uint(s) >= thrBits) {
          if (pos < CAND_CAP) { cand_idx[pos] = (rowb + r) * D_SAE + col; cand_sc[pos] = s; }
          pos++;
        }
      }
    }
  }
}

// ---------- fallback 128^2 GEMM (small ws): MODE 0 = hist (1/16), MODE 1 = extract ----------
template <int MODE>
__global__ __launch_bounds__(256) void mfma_gemm(
    const float* __restrict__ Wenc,
    const short* __restrict__ Ahi, const short* __restrict__ Alo,
    const float* __restrict__ benc, const float* __restrict__ g32,
    int* __restrict__ ghist, int* __restrict__ ctrl,
    int* __restrict__ cand_idx, float* __restrict__ cand_sc) {
  __shared__ short sA[8192];
  __shared__ short sB[8192];
  __shared__ int h[(MODE == 0) ? 2048 : 2];
  const int tid = threadIdx.x;
  const int lane = tid & 63;
  const int w = tid >> 6;
  const int wm = (w >> 1) * 64, wn = (w & 1) * 64;
  int lin = blockIdx.x;
  int mt, nt;
  if (MODE == 0) { mt = lin >> 7; nt = lin & 127; }
  else { int xcd = lin & 7, j = lin >> 3; mt = j & 31; nt = (xcd << 4) | (j >> 5); }
  const int row0 = mt * 128, col0 = nt * 128;
  if (MODE == 0) { for (int i = tid; i < 2048; i += 256) h[i] = 0; }
  else if (tid == 0) h[0] = 0;
  const int nl = tid & 127;
  const int half = tid >> 7;
  const float* wbase = Wenc + (size_t)col0 + nl;
  const size_t atile = (size_t)mt * 131072;
  f32x4 acc[4][4] = {};
  const int kcl = lane >> 4, l15 = lane & 15;
  float4 a0, a1, a2, a3;
  float bfv[16];
  {
    const float4* ah4 = (const float4*)(Ahi + atile);
    const float4* al4 = (const float4*)(Alo + atile);
    a0 = ah4[tid]; a1 = ah4[tid + 256];
    a2 = al4[tid]; a3 = al4[tid + 256];
#pragma unroll
    for (int p = 0; p < 4; ++p)
#pragma unroll
      for (int i = 0; i < 4; ++i)
        bfv[p * 4 + i] = wbase[(size_t)(p * 8 + half * 4 + i) * D_SAE];
  }
  for (int ks = 0; ks < 32; ++ks) {
    short hb[16], lb[16];
#pragma unroll
    for (int q = 0; q < 16; ++q) {
      unsigned short hh = f2bf(bfv[q]);
      hb[q] = (short)hh;
      lb[q] = (short)f2bf(bfv[q] - bf2f(hh));
    }
    __syncthreads();
    *(float4*)&sA[(size_t)tid * 8] = a0;
    *(float4*)&sA[(size_t)(tid + 256) * 8] = a1;
    *(float4*)&sA[(size_t)(512 + tid) * 8] = a2;
    *(float4*)&sA[(size_t)(512 + tid + 256) * 8] = a3;
#pragma unroll
    for (int p = 0; p < 4; ++p) {
      int boff = p * 1024 + nl * 8 + half * 4;
      *(short4*)&sB[boff] = make_short4(hb[p * 4], hb[p * 4 + 1], hb[p * 4 + 2], hb[p * 4 + 3]);
      *(short4*)&sB[4096 + boff] = make_short4(lb[p * 4], lb[p * 4 + 1], lb[p * 4 + 2], lb[p * 4 + 3]);
    }
    __syncthreads();
    if (ks < 31) {
      const float4* ah4 = (const float4*)(Ahi + atile + (ks + 1) * 4096);
      const float4* al4 = (const float4*)(Alo + atile + (ks + 1) * 4096);
      a0 = ah4[tid]; a1 = ah4[tid + 256];
      a2 = al4[tid]; a3 = al4[tid + 256];
      const int k0n = (ks + 1) * 32;
#pragma unroll
      for (int p = 0; p < 4; ++p)
#pragma unroll
        for (int i = 0; i < 4; ++i)
          bfv[p * 4 + i] = wbase[(size_t)(k0n + p * 8 + half * 4 + i) * D_SAE];
    }
    bf16x8 ahf[4], alf[4];
#pragma unroll
    for (int fm = 0; fm < 4; ++fm) {
      int off = (kcl * 128 + wm + fm * 16 + l15) * 8;
      ahf[fm] = *(const bf16x8*)&sA[off];
      alf[fm] = *(const bf16x8*)&sA[4096 + off];
    }
#pragma unroll
    for (int fn = 0; fn < 4; ++fn) {
      int boff = (kcl * 128 + wn + fn * 16 + l15) * 8;
      bf16x8 bh = *(const bf16x8*)&sB[boff];
      bf16x8 bl = *(const bf16x8*)&sB[4096 + boff];
#pragma unroll
      for (int fm = 0; fm < 4; ++fm) {
        acc[fm][fn] = __builtin_amdgcn_mfma_f32_16x16x32_bf16(ahf[fm], bh, acc[fm][fn], 0, 0, 0);
        acc[fm][fn] = __builtin_amdgcn_mfma_f32_16x16x32_bf16(alf[fm], bh, acc[fm][fn], 0, 0, 0);
        acc[fm][fn] = __builtin_amdgcn_mfma_f32_16x16x32_bf16(ahf[fm], bl, acc[fm][fn], 0, 0, 0);
      }
    }
  }
  const int l4r = lane >> 4;
  if (MODE == 0) {
#pragma unroll
    for (int fn = 0; fn < 4; ++fn) {
      int col = col0 + wn + fn * 16 + l15;
      float g = g32[col], be = benc[col];
#pragma unroll
      for (int fm = 0; fm < 4; ++fm) {
#pragma unroll
        for (int r = 0; r < 4; ++r) {
          float z = acc[fm][fn][r] + be;
          float s = z > 0.f ? z * g : 0.f;
          unsigned bits = __float_as_uint(s);
          if (bits) atomicAdd(&h[bits >> 21], 1);
        }
      }
    }
    __syncthreads();
    for (int i = tid; i < 2048; i += 256)
      if (h[i]) atomicAdd(&ghist[i], h[i]);
  } else {
    unsigned thrBits = (unsigned)ctrl[1];
    int cnt = 0;
#pragma unroll
    for (int fn = 0; fn < 4; ++fn) {
      int col = col0 + wn + fn * 16 + l15;
      float g = g32[col], be = benc[col];
#pragma unroll
      for (int fm = 0; fm < 4; ++fm) {
#pragma unroll
        for (int r = 0; r < 4; ++r) {
          float z = acc[fm][fn][r] + be;
          float s = z > 0.f ? z * g : 0.f;
          cnt += (__float_as_uint(s) >= thrBits) ? 1 : 0;
        }
      }
    }
    int my = 0;
    if (cnt) my = atomicAdd(&h[0], cnt);
    __syncthreads();
    if (tid == 0) h[1] = atomicAdd(&ctrl[2], h[0]);
    __syncthreads();
    int pos = h[1] + my;
#pragma unroll
    for (int fn = 0; fn < 4; ++fn) {
      int col = col0 + wn + fn * 16 + l15;
      float g = g32[col], be = benc[col];
#pragma unroll
      for (int fm = 0; fm < 4; ++fm) {
        int rowb = row0 + wm + fm * 16 + l4r * 4;
#pragma unroll
        for (int r = 0; r < 4; ++r) {
          float z = acc[fm][fn][r] + be;
          float s = z > 0.f ? z * g : 0.f;
          if (__float_as_uint(s) >= thrBits) {
            if (pos < CAND_CAP) { cand_idx[pos] = (rowb + r) * D_SAE + col; cand_sc[pos] = s; }
            pos++;
          }
        }
      }
    }
  }
}

// ---------- coarse threshold (64-thread parallel scan) ----------
__global__ void find_coarse_kernel(const int* __restrict__ gh, int* ctrl,
                                   const int* __restrict__ kptr, int sub) {
  long long kB = (long long)kptr[0] * BATCH;
  long long needl = (kB + 500000 + sub - 1) / sub;
  long long fl = 720000 / sub;
  if (needl < fl) needl = fl;
  int b, cum;
  hist_scan_desc(gh, 2048, (int)needl, b, cum);
  if (threadIdx.x == 0) {
    long long est_incl = (long long)sub * (cum + gh[b]);
    if (est_incl > 3500000LL && (long long)sub * cum >= kB + 120000LL) b = b + 1;
    ctrl[1] = (int)(((unsigned)b) << 21);
  }
}

// ---------- radix histograms over candidate scores (passes 1,2) ----------
__global__ __launch_bounds__(256) void chist_kernel(const float* __restrict__ cand_sc,
                                                    const int* __restrict__ ctrl,
                                                    int* __restrict__ ghist, int pass) {
  __shared__ int h[2048];
  int nb = (pass == 2) ? 1024 : 2048;
  for (int i = threadIdx.x; i < nb; i += 256) h[i] = 0;
  __syncthreads();
  int n = ctrl[2]; if (n > CAND_CAP) n = CAND_CAP;
  unsigned sel1 = 0, sel22 = 0;
  if (pass == 1) sel1 = (unsigned)ctrl[3];
  if (pass == 2) sel22 = ((unsigned)ctrl[3] << 11) | (unsigned)ctrl[5];
  for (int i = blockIdx.x * 256 + threadIdx.x; i < n; i += gridDim.x * 256) {
    unsigned bits = __float_as_uint(cand_sc[i]);
    if (pass == 0) atomicAdd(&h[bits >> 21], 1);
    else if (pass == 1) { if ((bits >> 21) == sel1) atomicAdd(&h[(bits >> 10) & 0x7FFu], 1); }
    else { if ((bits >> 10) == sel22) atomicAdd(&h[bits & 0x3FFu], 1); }
  }
  __syncthreads();
  for (int i = threadIdx.x; i < nb; i += 256)
    if (h[i]) atomicAdd(&ghist[i], h[i]);
}

// ---------- radix select step (64-thread parallel scan) ----------
__global__ void cfind_kernel(const int* __restrict__ hist, int* ctrl,
                             const int* __restrict__ kptr, int pass) {
  int kB = kptr[0] * BATCH;
  int need, nbins;
  if (pass == 0)      { need = kB;                       nbins = 2048; }
  else if (pass == 1) { need = kB - ctrl[4];             nbins = 2048; }
  else                { need = kB - ctrl[4] - ctrl[6];   nbins = 1024; }
  int b, cum;
  hist_scan_desc(hist, nbins, need, b, cum);
  if (threadIdx.x == 0) {
    if (pass == 0)      { ctrl[3] = b; ctrl[4] = cum; }
    else if (pass == 1) { ctrl[5] = b; ctrl[6] = cum; }
    else {
      unsigned vbits = ((unsigned)ctrl[3] << 21) | ((unsigned)ctrl[5] << 10) | (unsigned)b;
      float V = __uint_as_float(vbits);
      float* cf = (float*)ctrl;
      cf[8] = V; cf[9] = V + EPS_M; cf[10] = V - EPS_M;
    }
  }
}

// ---------- band partition ----------
__global__ __launch_bounds__(256) void band_kernel(const int* __restrict__ cand_idx,
    const float* __restrict__ cand_sc, const float* __restrict__ g32,
    int* ctrl, int* row_cnt, int* row_feat, float* row_act, int* cand2_idx) {
  const float* cf = (const float*)ctrl;
  float hi = cf[9], lo = cf[10];
  int n = ctrl[2]; if (n > CAND_CAP) n = CAND_CAP;
  int lane = threadIdx.x & 63;
  int defc = 0;
  for (int i = blockIdx.x * 256 + threadIdx.x; i < n; i += gridDim.x * 256) {
    float s = cand_sc[i];
    int flat = cand_idx[i];
    if (s > hi) {
      int b = flat >> 14, j = flat & (D_SAE - 1);
      int p = atomicAdd(&row_cnt[b], 1);
      if (p < ROW_CAP) { row_feat[b * ROW_CAP + p] = j; row_act[b * ROW_CAP + p] = s / g32[j]; }
      defc++;
    }
    bool isc = (s <= hi) && (s >= lo);
    int pos = wave_append(isc, &ctrl[12]);
    if (isc && pos >= 0 && pos < CAND2_CAP) cand2_idx[pos] = flat;
  }
#pragma unroll
  for (int off = 32; off > 0; off >>= 1) defc += __shfl_down(defc, off, 64);
  if (lane == 0 && defc) atomicAdd(&ctrl[11], defc);
}

// ---------- fp64 rescore of band candidates ----------
__global__ __launch_bounds__(256) void cand2_score_kernel(const int* __restrict__ ctrl,
    const int* __restrict__ cand2_idx, const float* __restrict__ x,
    const float* __restrict__ Wdec, const float* __restrict__ benc,
    const double* __restrict__ g64, double* __restrict__ cand2_sc) {
  __shared__ double lds[4];
  int n2 = ctrl[12]; if (n2 > CAND2_CAP) n2 = CAND2_CAP;
  int t = threadIdx.x;
  for (int c = blockIdx.x; c < n2; c += gridDim.x) {
    int flat = cand2_idx[c];
    int b = flat >> 14, j = flat & (D_SAE - 1);
    double d[4];
    ln_row_fp64(x + (size_t)b * (2 * D_MODEL), lds, d);
    float4 w4 = *(const float4*)(Wdec + (size_t)j * D_MODEL + t * 4);
    double a = d[0] * (double)w4.x + d[1] * (double)w4.y + d[2] * (double)w4.z + d[3] * (double)w4.w;
    double z = blockReduceSum256(a, lds) + (double)benc[j];
    double sc = z > 0 ? z * g64[j] : 0.0;
    if (t == 0) cand2_sc[c] = sc;
  }
}

// ---------- rank band candidates (fp64, index-stable), accept fill ----------
__global__ __launch_bounds__(256) void cand2_rank_kernel(const int* __restrict__ ctrl,
    const int* __restrict__ cand2_idx, const double* __restrict__ cand2_sc,
    const double* __restrict__ g64, const int* __restrict__ kptr,
    int* row_cnt, int* row_feat, float* row_act) {
  __shared__ int lds[4];
  int n2 = ctrl[12]; if (n2 > CAND2_CAP) n2 = CAND2_CAP;
  int kB = kptr[0] * BATCH;
  int fill = kB - ctrl[11];
  int t = threadIdx.x;
  for (int c = blockIdx.x; c < n2; c += gridDim.x) {
    double sc = cand2_sc[c];
    int fc = cand2_idx[c];
    int cnt = 0;
    for (int y = t; y < n2; y += 256) {
      double sy = cand2_sc[y];
      if (sy > sc || (sy == sc && cand2_idx[y] < fc)) cnt++;
    }
    cnt = blockReduceSumInt256(cnt, lds);
    if (t == 0 && cnt < fill) {
      int b = fc >> 14, j = fc & (D_SAE - 1);
      int p = atomicAdd(&row_cnt[b], 1);
      if (p < ROW_CAP) { row_feat[b * ROW_CAP + p] = j; row_act[b * ROW_CAP + p] = (float)(sc / g64[j]); }
    }
  }
}

// ---------- sparse recon (float4, 2-way ILP) ----------
__global__ __launch_bounds__(256) void recon_kernel(const int* __restrict__ row_cnt,
    const int* __restrict__ row_feat, const float* __restrict__ row_act,
    const float* __restrict__ Wdec, const float* __restrict__ bdec, float* __restrict__ out) {
  int b = blockIdx.x, t = threadIdx.x;
  float4 acc0 = *(const float4*)&bdec[t * 4];
  float4 acc1 = make_float4(0.f, 0.f, 0.f, 0.f);
  int n = row_cnt[b]; if (n > ROW_CAP) n = ROW_CAP;
  const int* rf = row_feat + (size_t)b * ROW_CAP;
  const float* ra = row_act + (size_t)b * ROW_CAP;
  int p = 0;
  for (; p + 2 <= n; p += 2) {
    int j0 = rf[p], j1 = rf[p + 1];
    float v0 = ra[p], v1 = ra[p + 1];
    float4 w0 = *(const float4*)(Wdec + (size_t)j0 * D_MODEL + t * 4);
    float4 w1 = *(const float4*)(Wdec + (size_t)j1 * D_MODEL + t * 4);
    acc0.x += v0 * w0.x; acc0.y += v0 * w0.y; acc0.z += v0 * w0.z; acc0.w += v0 * w0.w;
    acc1.x += v1 * w1.x; acc1.y += v1 * w1.y; acc1.z += v1 * w1.z; acc1.w += v1 * w1.w;
  }
  if (p < n) {
    int j0 = rf[p]; float v0 = ra[p];
    float4 w0 = *(const float4*)(Wdec + (size_t)j0 * D_MODEL + t * 4);
    acc0.x += v0 * w0.x; acc0.y += v0 * w0.y; acc0.z += v0 * w0.z; acc0.w += v0 * w0.w;
  }
  acc0.x += acc1.x; acc0.y += acc1.y; acc0.z += acc1.z; acc0.w += acc1.w;
  *(float4*)(out + (size_t)b * D_MODEL + t * 4) = acc0;
}

extern "C" void kernel_launch(void* const* d_in, const int* in_sizes, int n_in,
                              void* d_out, int out_size, void* d_ws, size_t ws_size,
                              hipStream_t stream) {
  const float* x    = (const float*)d_in[0];
  const float* Wenc = (const float*)d_in[1];
  const float* benc = (const float*)d_in[2];
  const float* Wdec = (const float*)d_in[3];
  const float* bdec = (const float*)d_in[4];
  const int*   kptr = (const int*)d_in[5];
  float* out = (float*)d_out;

  char* ws = (char*)d_ws;
  size_t off = 0;
  short*  Ahi       = (short*)(ws + off);  off += (size_t)BATCH * D_MODEL * 2;
  short*  Alo       = (short*)(ws + off);  off += (size_t)BATCH * D_MODEL * 2;
  int*    cand_idx  = (int*)(ws + off);    off += (size_t)CAND_CAP * 4;
  float*  cand_sc   = (float*)(ws + off);  off += (size_t)CAND_CAP * 4;
  int*    row_feat  = (int*)(ws + off);    off += (size_t)BATCH * ROW_CAP * 4;
  float*  row_act   = (float*)(ws + off);  off += (size_t)BATCH * ROW_CAP * 4;
  int*    cand2_idx = (int*)(ws + off);    off += (size_t)CAND2_CAP * 4;
  double* cand2_sc  = (double*)(ws + off); off += (size_t)CAND2_CAP * 8;
  double* g64       = (double*)(ws + off); off += (size_t)D_SAE * 8;
  float*  g32       = (float*)(ws + off);  off += (size_t)D_SAE * 4;
  char*   zbase     = ws + off;
  int* ghist   = (int*)(zbase);
  int* h1      = (int*)(zbase + 8192);
  int* h2      = (int*)(zbase + 16384);
  int* h3      = (int*)(zbase + 24576);
  int* ctrl    = (int*)(zbase + 28672);
  int* row_cnt = (int*)(zbase + 28928);
  size_t zbytes = 28928 + (size_t)BATCH * 4;
  size_t small_need = off + zbytes;
  if (small_need > ws_size) return;  // ~60 MB floor

  size_t big_off = (small_need + 255) & ~(size_t)255;
  short* Whi = (short*)(ws + big_off);
  short* Wlo = Whi + (size_t)D_MODEL * D_SAE;
  size_t big_need = big_off + (size_t)D_MODEL * D_SAE * 4;
  const bool big = (big_need <= ws_size);   // round-6/8-proven to fit

  hipMemsetAsync(zbase, 0, zbytes, stream);

  ln_kernel<<<BATCH, 256, 0, stream>>>(x, Ahi, Alo);
  norm_kernel<<<D_SAE, 256, 0, stream>>>(Wdec, g64, g32);
  if (big) {
    wsplit_kernel<<<4096, 256, 0, stream>>>(Wenc, Whi, Wlo);
    hist_gemm<<<512, 256, 0, stream>>>(Whi, Ahi, benc, g32, ghist);
    find_coarse_kernel<<<1, 64, 0, stream>>>(ghist, ctrl, kptr, 8);
    mfma_gemm256<<<1024, 512, 0, stream>>>(Whi, Wlo, Ahi, Alo, benc, g32, ctrl, cand_idx, cand_sc, h1);
  } else {
    mfma_gemm<0><<<256, 256, 0, stream>>>(Wenc, Ahi, Alo, benc, g32, ghist, ctrl, nullptr, nullptr);
    find_coarse_kernel<<<1, 64, 0, stream>>>(ghist, ctrl, kptr, 16);
    mfma_gemm<1><<<4096, 256, 0, stream>>>(Wenc, Ahi, Alo, benc, g32, nullptr, ctrl, cand_idx, cand_sc);
    chist_kernel<<<1024, 256, 0, stream>>>(cand_sc, ctrl, h1, 0);
  }
  cfind_kernel<<<1, 64, 0, stream>>>(h1, ctrl, kptr, 0);
  chist_kernel<<<1024, 256, 0, stream>>>(cand_sc, ctrl, h2, 1);
  cfind_kernel<<<1, 64, 0, stream>>>(h2, ctrl, kptr, 1);
  chist_kernel<<<1024, 256, 0, stream>>>(cand_sc, ctrl, h3, 2);
  cfind_kernel<<<1, 64, 0, stream>>>(h3, ctrl, kptr, 2);
  band_kernel<<<1024, 256, 0, stream>>>(cand_idx, cand_sc, g32, ctrl, row_cnt, row_feat, row_act, cand2_idx);
  cand2_score_kernel<<<4096, 256, 0, stream>>>(ctrl, cand2_idx, x, Wdec, benc, g64, cand2_sc);
  cand2_rank_kernel<<<2048, 256, 0, stream>>>(ctrl, cand2_idx, cand2_sc, g64, kptr, row_cnt, row_feat, row_act);
  recon_kernel<<<BATCH, 256, 0, stream>>>(row_cnt, row_feat, row_act, Wdec, bdec, out);
}